// Round 8
// baseline (194.351 us; speedup 1.0000x reference)
//
#include <hip/hip_runtime.h>
#include <stdint.h>

// ---------------- problem constants ----------------
#define TT 262144
#define KK 32
#define DD 64
#define LSTEP 32               // scan steps per chunk
#define PCH 8192               // chunks (transitions t=1..T-1; last chunk has 31 steps)

typedef __attribute__((ext_vector_type(4)))  float f4v;
typedef __attribute__((ext_vector_type(16))) float f16v;
typedef __attribute__((ext_vector_type(4)))  short s4v;
typedef __attribute__((ext_vector_type(8)))  short s8v;
typedef __attribute__((ext_vector_type(8)))  __bf16 bf8v;
typedef __attribute__((ext_vector_type(2)))  unsigned int u2v;
typedef __attribute__((ext_vector_type(4)))  unsigned int u4v;

// ---------------- ws layout ----------------
// ushort-unit offsets (prep region)
#define WS_AFRAG_US 0          // ushort[1024] : Anorm^T frags [g2:2][lane:64][e:8] (K=16 order)
#define WS_WFRAG_US 1024       // ushort[4096] : W frags      [s2:8][lane:64][e:8] (K=16 order)
// float-unit offsets
#define WS_WF    2560          // float[4096]  : W fp32 [dd:128][k:32] (for k3 ll0)
#define WS_CK    6656          // float[32]
#define WS_AM1   6688          // float[32]
#define WS_BB    6720          // float[32]
#define WS_PI0   6752          // float[32]
#define WS_LS    8192          // float[PCH]   : chunk log-scales
#define WS_LS2   16384         // float[128]   : group log-scales
// short-unit offsets (matrix storage, bf16); lane's 16 ushorts = [old g:4][e:4];
// K=16 frag g2 = shorts 8*g2..8*g2+7 (concat of old K=8 frags 2g2, 2g2+1)
#define SH_MATS  33280                  // ushort[PCH*1024]  : chunk mats
#define SH_MATS2 (33280 + PCH*1024)     // ushort[128*1024]  : group mats
#define LN2F 0.69314718055994531f

__device__ __forceinline__ unsigned pkbf(float hi, float lo) {
    return __builtin_amdgcn_perm(__builtin_bit_cast(unsigned, hi),
                                 __builtin_bit_cast(unsigned, lo), 0x07060302u);
}
__device__ __forceinline__ unsigned short f2bf_rne(float f) {
    unsigned u = __builtin_bit_cast(unsigned, f);
    unsigned r = u + 0x7FFFu + ((u >> 16) & 1u);
    return (unsigned short)(r >> 16);
}
__device__ __forceinline__ float bf2f(unsigned short u) {
    return __builtin_bit_cast(float, (unsigned)u << 16);
}
__device__ __forceinline__ float wmax32(float v) {
    v = fmaxf(v, __shfl_xor(v, 1));  v = fmaxf(v, __shfl_xor(v, 2));
    v = fmaxf(v, __shfl_xor(v, 4));  v = fmaxf(v, __shfl_xor(v, 8));
    v = fmaxf(v, __shfl_xor(v, 16));
    return v;
}
__device__ __forceinline__ float wmax64(float v) {
    v = wmax32(v); v = fmaxf(v, __shfl_xor(v, 32));
    return v;
}
__device__ __forceinline__ float wsum32(float v) {
    v += __shfl_xor(v, 1); v += __shfl_xor(v, 2); v += __shfl_xor(v, 4);
    v += __shfl_xor(v, 8); v += __shfl_xor(v, 16);
    return v;
}
__device__ __forceinline__ float wsum64(float v) {
    v = wsum32(v); v += __shfl_xor(v, 32);
    return v;
}
__device__ __forceinline__ float wval(int dd, int k, const float* mu, const float* lsg) {
    int d = dd & 63;
    float lv = lsg[k * DD + d];
    float iv = __expf(-2.f * lv);
    return (dd < DD) ? (-0.5f * iv) : (mu[k * DD + d] * iv);
}
// gfx950 K=16 bf16 MFMA (full-rate; the _1k K=8 op occupies the same pipe slot for half the FLOPs)
__device__ __forceinline__ f16v mfma16(s8v a, s8v b, f16v c) {
    return __builtin_amdgcn_mfma_f32_32x32x16_bf16(
        __builtin_bit_cast(bf8v, a), __builtin_bit_cast(bf8v, b), c, 0, 0, 0);
}

// ================= k0: constants / fragment preformat =================
__global__ void k0_prep(const float* __restrict__ Y, const float* __restrict__ A,
                        const float* __restrict__ lab, const float* __restrict__ mu,
                        const float* __restrict__ lsg, const float* __restrict__ pi,
                        float* __restrict__ ws, float* __restrict__ out)
{
    __shared__ float lseA[KK];
    const int tid = threadIdx.x;
    if (tid < KK) {
        float m = -1e30f;
        for (int j = 0; j < KK; ++j) m = fmaxf(m, A[tid * KK + j]);
        float s = 0.f;
        for (int j = 0; j < KK; ++j) s += __expf(A[tid * KK + j] - m);
        lseA[tid] = m + __logf(s);

        float mp = -1e30f;
        for (int j = 0; j < KK; ++j) mp = fmaxf(mp, pi[j]);
        float sp = 0.f;
        for (int j = 0; j < KK; ++j) sp += __expf(pi[j] - mp);
        ws[WS_PI0 + tid] = pi[tid] - (mp + __logf(sp));

        float la = lab[tid * 2 + 0], lb = lab[tid * 2 + 1];
        float a = __expf(la), b = __expf(lb);
        float c1 = 0.f, c2 = 0.f;
        for (int d = 0; d < DD; ++d) {
            float lv = lsg[tid * DD + d];
            float mv = mu[tid * DD + d];
            c1 -= lv;
            c2 += mv * mv * __expf(-2.f * lv);
        }
        ws[WS_CK + tid]  = a * lb - lgammaf(a) + c1 - 0.5f * c2 - 32.f * 1.8378770664093453f;
        ws[WS_AM1 + tid] = a - 1.f;
        ws[WS_BB + tid]  = b;
    }
    __syncthreads();
    unsigned short* us = (unsigned short*)ws;
    // A frags, K=16 order: [g2:2][lane:64][e:8]; k = 16*g2 + 8*(e>>2) + 4*h + (e&3)
    for (int idx = tid; idx < 1024; idx += 256) {
        int g2 = idx >> 9, rem = idx & 511, ln = rem >> 3, e = rem & 7;
        int m = 16 * g2 + 8 * (e >> 2) + 4 * (ln >> 5) + (e & 3), i = ln & 31;
        us[WS_AFRAG_US + idx] = f2bf_rne(__expf(A[m * KK + i] - lseA[m]));
    }
    // W frags, K=16 order: [s2:8][lane:64][e:8]; dd = 16*s2 + 8*(e>>2) + 4*h + (e&3)
    // s2 0..3 pair with y^2 (dd 0..63), s2 4..7 pair with y (dd 64..127)
    for (int idx = tid; idx < 4096; idx += 256) {
        int s2 = idx >> 9, rem = idx & 511, ln = rem >> 3, e = rem & 7;
        int dd = 16 * s2 + 8 * (e >> 2) + 4 * (ln >> 5) + (e & 3);
        us[WS_WFRAG_US + idx] = f2bf_rne(wval(dd, ln & 31, mu, lsg));
    }
    for (int idx = tid; idx < 4096; idx += 256) {
        int dd = idx >> 5, k = idx & 31;
        ws[WS_WF + idx] = wval(dd, k, mu, lsg);
    }
    if (tid < DD) out[tid] = Y[tid];   // h row 0
}

// ================= k1: chunk scan (1 wave = 2 chunks, interleaved chains) =================
// R5 memory structure (verified 62us twice: coalesced 1KB-segment staging into bf16
// frags, fused h write, f32 E stride-36 aliasing dead Y, shfl reductions) with TWO
// independent scan chains per wave interleaved at instruction level. Every stall of
// chain A's pack->MFMA->MFMA->mul / rescale chain is fillable by chain B within the
// same wave -- ILP that does not depend on the CU wave scheduler (which rounds 2-7
// proved does not fill these stalls from other waves).
__global__ __launch_bounds__(256, 4) void k1_scan(
    const float* __restrict__ Y, const float* __restrict__ dTp,
    float* __restrict__ ws, float* __restrict__ out)
{
    __shared__ __align__(16) float Ebuf[4][2304];        // per wave: 2 chains x (Ybf 4KB | E 4.5KB)
    __shared__ __align__(16) float dtv[4][64], dtl[4][64];

    const int tid = threadIdx.x;
    const int wv = tid >> 6, l = tid & 63, h = l >> 5, c = l & 31;
    const int p2 = blockIdx.x * 4 + wv;          // 0..4095
    const int pA = p2 * 2, pB = pA + 1;
    const int t0A = 1 + pA * LSTEP;              // t0B = t0A + LSTEP
    const int nsB = (p2 == PCH / 2 - 1) ? (TT - (t0A + LSTEP)) : LSTEP;  // 31 on last wave

    const unsigned short* afr = (const unsigned short*)ws + WS_AFRAG_US;
    const unsigned short* wfr = (const unsigned short*)ws + WS_WFRAG_US;

    const float cK = ws[WS_CK + c], am1 = ws[WS_AM1 + c], bb = ws[WS_BB + c];

    {   // dT staging: 64 lanes cover both chunks (contiguous)
        int t = t0A + l;
        float dv = (t < TT) ? dTp[t] : 1.f;
        dtv[wv][l] = dv;
        dtl[wv][l] = __logf(dv);
    }

    f16v zf;
    #pragma unroll
    for (int r = 0; r < 16; ++r) zf[r] = 0.f;

    unsigned short* Ybase = (unsigned short*)&Ebuf[wv][0];   // chain ch at ushort ch*2304
    float* Ewave = &Ebuf[wv][0];                              // chain ch E at float ch*1152

    // ---- coalesced Y stage (64 rows = both chunks) -> LDS bf16 frags, fused h write ----
    {
        const size_t gbase = (size_t)t0A * DD;
        const int rr = l & 3, cb = l >> 2;
        const int g2s = cb >> 2, bs = (cb >> 1) & 1, hs = cb & 1;
        #pragma unroll
        for (int i = 0; i < 16; ++i) {
            const size_t gi = gbase + (size_t)i * 256 + (size_t)(rr * 64 + cb * 4);
            f4v y4; y4[0] = 0.f; y4[1] = 0.f; y4[2] = 0.f; y4[3] = 0.f;
            const bool ok = gi < (size_t)TT * DD;
            if (ok) y4 = *(const f4v*)(Y + gi);
            if (ok) *(f4v*)(out + gi) = y4;
            const int r = i * 4 + rr;                   // 0..63; chain = r>>5 (uniform per i)
            const int off = (i >> 3) * 2304 + g2s * 512 + (32 * hs + (r & 31)) * 8 + 4 * bs;
            u2v pw; pw[0] = pkbf(y4[1], y4[0]); pw[1] = pkbf(y4[3], y4[2]);
            *(u2v*)(Ybase + off) = pw;
        }
    }
    asm volatile("s_waitcnt lgkmcnt(0)" ::: "memory");  // frag writes visible to own wave

    // ---- emission ll tiles via K=16 MFMA; raw-y frag IS the LDS read ----
    auto emit = [&](int ch) -> f16v {
        const unsigned short* Yb = Ybase + ch * 2304;
        f16v a = zf;
        s8v raws[4];
        #pragma unroll
        for (int g2 = 0; g2 < 4; ++g2) {
            const s8v yf = *(const s8v*)(Yb + g2 * 512 + l * 8);
            raws[g2] = yf;
            u4v qp;
            #pragma unroll
            for (int e2 = 0; e2 < 4; ++e2) {
                const float f0 = bf2f((unsigned short)yf[2 * e2]);
                const float f1 = bf2f((unsigned short)yf[2 * e2 + 1]);
                qp[e2] = pkbf(f1 * f1, f0 * f0);
            }
            const s8v wf = *(const s8v*)(wfr + g2 * 512 + l * 8);
            a = mfma16(__builtin_bit_cast(s8v, qp), wf, a);
        }
        #pragma unroll
        for (int g2 = 0; g2 < 4; ++g2) {
            const s8v wf = *(const s8v*)(wfr + (4 + g2) * 512 + l * 8);
            a = mfma16(raws[g2], wf, a);
        }
        return a;
    };
    const f16v accA = emit(0);
    const f16v accB = emit(1);

    // ---- A^T frags (two K=16 groups) ----
    const s8v aF0 = *(const s8v*)(afr + l * 8);
    const s8v aF1 = *(const s8v*)(afr + 512 + l * 8);

    // ---- ll -> c_t, e = exp(ll-c) into E_ch (aliases dead Ybf_ch) ----
    auto llphase = [&](const f16v& acc, int ch, int nsteps) -> float {
        float* E = Ewave + ch * 1152;
        const float* dv = &dtv[wv][ch * 32];
        const float* dl = &dtl[wv][ch * 32];
        float csv = 0.f;
        #pragma unroll
        for (int m = 0; m < 4; ++m) {
            const f4v dv4 = *(const f4v*)(dv + 8 * m + 4 * h);
            const f4v dl4 = *(const f4v*)(dl + 8 * m + 4 * h);
            #pragma unroll
            for (int j = 0; j < 4; ++j) {
                const int row = 8 * m + 4 * h + j;
                float llv = acc[4 * m + j] + cK + am1 * dl4[j] - bb * dv4[j];
                float cm = wmax32(llv);
                E[row * 36 + c] = __expf(llv - cm);
                csv += (row < nsteps) ? cm : 0.f;
            }
        }
        return wsum64(csv) * (1.f / 32.f);
    };
    const float caccA = llphase(accA, 0, LSTEP);
    const float caccB = llphase(accB, 1, nsB);

    asm volatile("s_waitcnt lgkmcnt(0)" ::: "memory");  // E visible to own wave

    // ---- dual interleaved scan: S <- diag(e_t) * Anorm^T * S ----
    f16v SA, SB;
    #pragma unroll
    for (int m = 0; m < 4; ++m)
        #pragma unroll
        for (int j = 0; j < 4; ++j) {
            const float id = ((8 * m + 4 * h + j) == c) ? 1.f : 0.f;
            SA[4 * m + j] = id;
            SB[4 * m + j] = id;
        }
    float l2A = 0.f, l2B = 0.f;
    const float* EA = Ewave;
    const float* EB = Ewave + 1152;

    auto step = [&](f16v& S, const float* E, int n) {
        u4v b0, b1;
        b0[0] = pkbf(S[1],  S[0]);  b0[1] = pkbf(S[3],  S[2]);
        b0[2] = pkbf(S[5],  S[4]);  b0[3] = pkbf(S[7],  S[6]);
        b1[0] = pkbf(S[9],  S[8]);  b1[1] = pkbf(S[11], S[10]);
        b1[2] = pkbf(S[13], S[12]); b1[3] = pkbf(S[15], S[14]);
        f16v Dv = mfma16(aF0, __builtin_bit_cast(s8v, b0), zf);
        Dv = mfma16(aF1, __builtin_bit_cast(s8v, b1), Dv);
        #pragma unroll
        for (int m = 0; m < 4; ++m) {
            const f4v e4 = *(const f4v*)(E + n * 36 + 8 * m + 4 * h);  // 2-addr broadcast
            S[4 * m + 0] = Dv[4 * m + 0] * e4[0];
            S[4 * m + 1] = Dv[4 * m + 1] * e4[1];
            S[4 * m + 2] = Dv[4 * m + 2] * e4[2];
            S[4 * m + 3] = Dv[4 * m + 3] * e4[3];
        }
    };
    auto rescale = [&](f16v& S, float& l2) {
        float mx = S[0];
        #pragma unroll
        for (int r = 1; r < 16; ++r) mx = fmaxf(mx, S[r]);
        mx = wmax64(mx);
        const float inv = __fdividef(1.f, mx);
        #pragma unroll
        for (int r = 0; r < 16; ++r) S[r] *= inv;
        l2 += __log2f(mx);
    };

    if (p2 != PCH / 2 - 1) {
        #pragma unroll
        for (int n = 0; n < LSTEP; ++n) {
            step(SA, EA, n);
            step(SB, EB, n);
            if ((n & 3) == 3) { rescale(SA, l2A); rescale(SB, l2B); }
        }
    } else {
        for (int n = 0; n < LSTEP; ++n) {
            step(SA, EA, n);
            if (n < nsB) step(SB, EB, n);
            if ((n & 3) == 3) { rescale(SA, l2A); rescale(SB, l2B); }
        }
    }

    // ---- transpose S -> frag order bf16, coalesced store (E_ch dead) ----
    auto storemat = [&](const f16v& S, int ch, int p, float cacc, float l2) {
        unsigned short* Tb = (unsigned short*)(Ewave + ch * 1152);
        asm volatile("s_waitcnt lgkmcnt(0)" ::: "memory");
        #pragma unroll
        for (int m = 0; m < 4; ++m)
            #pragma unroll
            for (int j = 0; j < 4; ++j)
                Tb[(8 * m + 4 * h + j) * 36 + c] = f2bf_rne(S[4 * m + j]);
        asm volatile("s_waitcnt lgkmcnt(0)" ::: "memory");
        u2v tg0 = *(const u2v*)(Tb + c * 36 + 0  + 4 * h);
        u2v tg1 = *(const u2v*)(Tb + c * 36 + 8  + 4 * h);
        u2v tg2 = *(const u2v*)(Tb + c * 36 + 16 + 4 * h);
        u2v tg3 = *(const u2v*)(Tb + c * 36 + 24 + 4 * h);
        unsigned short* gm = (unsigned short*)ws + SH_MATS + (size_t)p * 1024 + l * 16;
        u4v s0; s0[0] = tg0[0]; s0[1] = tg0[1]; s0[2] = tg1[0]; s0[3] = tg1[1];
        u4v s1; s1[0] = tg2[0]; s1[1] = tg2[1]; s1[2] = tg3[0]; s1[3] = tg3[1];
        *(u4v*)(gm) = s0;
        *(u4v*)(gm + 8) = s1;
        if (l == 0) ws[WS_LS + p] = cacc + LN2F * l2;
    };
    storemat(SA, 0, pA, caccA, l2A);
    storemat(SB, 1, pB, caccB, l2B);
}

// ---- helper: one product step  U <- A_mat * U  (A from 2 uint4 regs = two K=16 frags) ----
__device__ __forceinline__ f16v prodAU(const u4v a0, const u4v a1, const f16v U, const f16v zf) {
    u4v b0, b1;
    b0[0] = pkbf(U[1],  U[0]);  b0[1] = pkbf(U[3],  U[2]);
    b0[2] = pkbf(U[5],  U[4]);  b0[3] = pkbf(U[7],  U[6]);
    b1[0] = pkbf(U[9],  U[8]);  b1[1] = pkbf(U[11], U[10]);
    b1[2] = pkbf(U[13], U[12]); b1[3] = pkbf(U[15], U[14]);
    f16v Dv = mfma16(__builtin_bit_cast(s8v, a0), __builtin_bit_cast(s8v, b0), zf);
    Dv = mfma16(__builtin_bit_cast(s8v, a1), __builtin_bit_cast(s8v, b1), Dv);
    return Dv;
}

// ================= k2: combine 64 chunk mats per block (2 waves x 32 + pair) =================
__global__ __launch_bounds__(128, 1) void k2_combine(float* __restrict__ ws)
{
    __shared__ __align__(16) unsigned short slot[2][1152];  // row-major, stride 36
    __shared__ float scl[2], lac[2];
    const int tid = threadIdx.x, wv = tid >> 6, l = tid & 63, h = l >> 5, c = l & 31;
    const int blk = blockIdx.x;
    const int idx0 = blk * 64 + wv * 32;
    const unsigned short* mats = (const unsigned short*)ws + SH_MATS;

    float lsv = (l < 32) ? ws[WS_LS + idx0 + l] : 0.f;
    float lssum = wsum64(lsv);

    f16v zf;
    #pragma unroll
    for (int r = 0; r < 16; ++r) zf[r] = 0.f;
    f16v U;
    #pragma unroll
    for (int m = 0; m < 4; ++m)
        #pragma unroll
        for (int j = 0; j < 4; ++j)
            U[4 * m + j] = ((8 * m + 4 * h + j) == c) ? 1.f : 0.f;
    float l2a = 0.f;

    u4v pf[2][2];
    {
        const u4v* mp0 = (const u4v*)(mats + (size_t)idx0 * 1024) + l * 2;
        const u4v* mp1 = (const u4v*)(mats + (size_t)(idx0 + 1) * 1024) + l * 2;
        pf[0][0] = mp0[0]; pf[0][1] = mp0[1];
        pf[1][0] = mp1[0]; pf[1][1] = mp1[1];
    }
    for (int q = 0; q < 32; ++q) {
        const u4v a0 = pf[q & 1][0], a1 = pf[q & 1][1];
        if (q + 2 < 32) {
            const u4v* mp = (const u4v*)(mats + (size_t)(idx0 + q + 2) * 1024) + l * 2;
            pf[q & 1][0] = mp[0]; pf[q & 1][1] = mp[1];
        }
        f16v Dv = prodAU(a0, a1, U, zf);
        if ((q & 3) == 3) {
            float mx = Dv[0];
            #pragma unroll
            for (int r = 1; r < 16; ++r) mx = fmaxf(mx, Dv[r]);
            mx = wmax64(mx);
            const float inv = __fdividef(1.f, mx);
            #pragma unroll
            for (int r = 0; r < 16; ++r) U[r] = Dv[r] * inv;
            l2a += __log2f(mx);
        } else {
            U = Dv;
        }
    }
    #pragma unroll
    for (int m = 0; m < 4; ++m)
        #pragma unroll
        for (int j = 0; j < 4; ++j)
            slot[wv][(8 * m + 4 * h + j) * 36 + c] = f2bf_rne(U[4 * m + j]);
    if (l == 0) { scl[wv] = lssum; lac[wv] = l2a; }
    __syncthreads();

    if (wv == 0) {
        u4v a0, a1;
        {
            u2v t0 = *(const u2v*)(&slot[1][c * 36 + 0 + 4 * h]);
            u2v t1 = *(const u2v*)(&slot[1][c * 36 + 8 + 4 * h]);
            u2v t2 = *(const u2v*)(&slot[1][c * 36 + 16 + 4 * h]);
            u2v t3 = *(const u2v*)(&slot[1][c * 36 + 24 + 4 * h]);
            a0[0] = t0[0]; a0[1] = t0[1]; a0[2] = t1[0]; a0[3] = t1[1];
            a1[0] = t2[0]; a1[1] = t2[1]; a1[2] = t3[0]; a1[3] = t3[1];
        }
        f16v Dv = prodAU(a0, a1, U, zf);
        float mx = Dv[0];
        #pragma unroll
        for (int r = 1; r < 16; ++r) mx = fmaxf(mx, Dv[r]);
        mx = wmax64(mx);
        const float inv = __fdividef(1.f, mx);
        #pragma unroll
        for (int r = 0; r < 16; ++r) U[r] = Dv[r] * inv;
        const float l2tot = lac[0] + lac[1] + __log2f(mx);
        asm volatile("s_waitcnt lgkmcnt(0)" ::: "memory");
        #pragma unroll
        for (int m = 0; m < 4; ++m)
            #pragma unroll
            for (int j = 0; j < 4; ++j)
                slot[0][(8 * m + 4 * h + j) * 36 + c] = f2bf_rne(U[4 * m + j]);
        asm volatile("s_waitcnt lgkmcnt(0)" ::: "memory");
        u2v tg[4];
        #pragma unroll
        for (int g = 0; g < 4; ++g)
            tg[g] = *(const u2v*)(&slot[0][c * 36 + 8 * g + 4 * h]);
        unsigned short* gm = (unsigned short*)ws + SH_MATS2 + (size_t)blk * 1024 + l * 16;
        u4v s0; s0[0] = tg[0][0]; s0[1] = tg[0][1]; s0[2] = tg[1][0]; s0[3] = tg[1][1];
        u4v s1; s1[0] = tg[2][0]; s1[1] = tg[2][1]; s1[2] = tg[3][0]; s1[3] = tg[3][1];
        *(u4v*)(gm) = s0;
        *(u4v*)(gm + 8) = s1;
        if (l == 0) ws[WS_LS2 + blk] = scl[0] + scl[1] + LN2F * l2tot;
    }
}

// ================= k3: 16 chains of 8 + LDS tree + final loss =================
__global__ __launch_bounds__(1024, 1) void k3_final(
    const float* __restrict__ Y, const float* __restrict__ dTp,
    float* __restrict__ ws, float* __restrict__ out)
{
    __shared__ __align__(16) unsigned short slot[16][1152];
    __shared__ float sc[16];
    const int tid = threadIdx.x, wv = tid >> 6, l = tid & 63, h = l >> 5, c = l & 31;
    const unsigned short* mats2 = (const unsigned short*)ws + SH_MATS2;

    f16v zf;
    #pragma unroll
    for (int r = 0; r < 16; ++r) zf[r] = 0.f;

    const int idx0 = wv * 8;
    float lsv = (l < 8) ? ws[WS_LS2 + idx0 + l] : 0.f;
    float lssum = wsum64(lsv);
    f16v U;
    #pragma unroll
    for (int m = 0; m < 4; ++m)
        #pragma unroll
        for (int j = 0; j < 4; ++j)
            U[4 * m + j] = ((8 * m + 4 * h + j) == c) ? 1.f : 0.f;
    float l2a = 0.f;
    u4v pf[2][2];
    {
        const u4v* mp0 = (const u4v*)(mats2 + (size_t)idx0 * 1024) + l * 2;
        const u4v* mp1 = (const u4v*)(mats2 + (size_t)(idx0 + 1) * 1024) + l * 2;
        pf[0][0] = mp0[0]; pf[0][1] = mp0[1];
        pf[1][0] = mp1[0]; pf[1][1] = mp1[1];
    }
    for (int q = 0; q < 8; ++q) {
        const u4v a0 = pf[q & 1][0], a1 = pf[q & 1][1];
        if (q + 2 < 8) {
            const u4v* mp = (const u4v*)(mats2 + (size_t)(idx0 + q + 2) * 1024) + l * 2;
            pf[q & 1][0] = mp[0]; pf[q & 1][1] = mp[1];
        }
        f16v Dv = prodAU(a0, a1, U, zf);
        if ((q & 3) == 3) {
            float mx = Dv[0];
            #pragma unroll
            for (int r = 1; r < 16; ++r) mx = fmaxf(mx, Dv[r]);
            mx = wmax64(mx);
            const float inv = __fdividef(1.f, mx);
            #pragma unroll
            for (int r = 0; r < 16; ++r) U[r] = Dv[r] * inv;
            l2a += __log2f(mx);
        } else {
            U = Dv;
        }
    }
    #pragma unroll
    for (int m = 0; m < 4; ++m)
        #pragma unroll
        for (int j = 0; j < 4; ++j)
            slot[wv][(8 * m + 4 * h + j) * 36 + c] = f2bf_rne(U[4 * m + j]);
    if (l == 0) sc[wv] = lssum + LN2F * l2a;
    __syncthreads();

    for (int s = 1; s < 16; s <<= 1) {
        const int cnt = 16 / (2 * s);
        if (wv < cnt) {
            const int i = wv * 2 * s;
            s8v aA0, aA1, bB0, bB1;
            {
                u2v t0 = *(const u2v*)(&slot[i + s][c * 36 + 0 + 4 * h]);
                u2v t1 = *(const u2v*)(&slot[i + s][c * 36 + 8 + 4 * h]);
                u2v t2 = *(const u2v*)(&slot[i + s][c * 36 + 16 + 4 * h]);
                u2v t3 = *(const u2v*)(&slot[i + s][c * 36 + 24 + 4 * h]);
                u4v a0; a0[0] = t0[0]; a0[1] = t0[1]; a0[2] = t1[0]; a0[3] = t1[1];
                u4v a1; a1[0] = t2[0]; a1[1] = t2[1]; a1[2] = t3[0]; a1[3] = t3[1];
                aA0 = __builtin_bit_cast(s8v, a0);
                aA1 = __builtin_bit_cast(s8v, a1);
                #pragma unroll
                for (int j = 0; j < 4; ++j) {
                    bB0[j]     = (short)slot[i][(0  + 4 * h + j) * 36 + c];
                    bB0[4 + j] = (short)slot[i][(8  + 4 * h + j) * 36 + c];
                    bB1[j]     = (short)slot[i][(16 + 4 * h + j) * 36 + c];
                    bB1[4 + j] = (short)slot[i][(24 + 4 * h + j) * 36 + c];
                }
            }
            f16v Dv = mfma16(aA0, bB0, zf);
            Dv = mfma16(aA1, bB1, Dv);
            float mx = Dv[0];
            #pragma unroll
            for (int r = 1; r < 16; ++r) mx = fmaxf(mx, Dv[r]);
            mx = wmax64(mx);
            const float inv = __fdividef(1.f, mx);
            #pragma unroll
            for (int m = 0; m < 4; ++m)
                #pragma unroll
                for (int j = 0; j < 4; ++j)
                    slot[i][(8 * m + 4 * h + j) * 36 + c] = f2bf_rne(Dv[4 * m + j] * inv);
            if (l == 0) sc[i] = sc[i] + sc[i + s] + __logf(mx);
        }
        __syncthreads();
    }

    if (wv == 0) {
        float acc = 0.f;
        const float* Wf = ws + WS_WF;
        for (int dd = 0; dd < 128; ++dd) {
            const float yv = Y[dd & 63];
            const float f = (dd < 64) ? yv * yv : yv;
            acc = fmaf(f, Wf[dd * 32 + c], acc);
        }
        const float dt0 = dTp[0];
        const float ll0 = acc + ws[WS_CK + c] + ws[WS_AM1 + c] * __logf(dt0) - ws[WS_BB + c] * dt0;
        const float av = ws[WS_PI0 + c] + ll0;
        const float c0 = wmax32(av);
        const float a0 = __expf(av - c0);
        float part = 0.f;
        #pragma unroll
        for (int i = 0; i < 16; ++i) {
            const int ii = 16 * h + i;
            const float m = bf2f(slot[0][c * 36 + ii]);
            const float ai = __shfl(a0, ii);
            part = fmaf(m, ai, part);
        }
        const float srow = part + __shfl_xor(part, 32);
        const float tot = wsum32(srow);
        if (l == 0) out[(size_t)TT * DD] = -(sc[0] + c0 + __logf(tot));
    }
}

// ================= launcher =================
extern "C" void kernel_launch(void* const* d_in, const int* in_sizes, int n_in,
                              void* d_out, int out_size, void* d_ws, size_t ws_size,
                              hipStream_t stream)
{
    const float* Y   = (const float*)d_in[0];
    const float* dTp = (const float*)d_in[1];
    const float* A   = (const float*)d_in[2];
    const float* lab = (const float*)d_in[3];
    const float* mu  = (const float*)d_in[4];
    const float* lsg = (const float*)d_in[5];
    const float* pi  = (const float*)d_in[6];
    float* out = (float*)d_out;
    float* ws  = (float*)d_ws;

    hipLaunchKernelGGL(k0_prep, dim3(1), dim3(256), 0, stream, Y, A, lab, mu, lsg, pi, ws, out);
    hipLaunchKernelGGL(k1_scan, dim3(PCH / 8), dim3(256), 0, stream, Y, dTp, ws, out);
    hipLaunchKernelGGL(k2_combine, dim3(128), dim3(128), 0, stream, ws);
    hipLaunchKernelGGL(k3_final, dim3(1), dim3(1024), 0, stream, Y, dTp, ws, out);
}

// Round 9
// 190.138 us; speedup vs baseline: 1.0222x; 1.0222x over previous
//
#include <hip/hip_runtime.h>
#include <stdint.h>

// ---------------- problem constants ----------------
#define TT 262144
#define KK 32
#define DD 64
#define LSTEP 32               // scan steps per chunk
#define PCH 8192               // chunks (transitions t=1..T-1; last chunk has 31 steps)

typedef __attribute__((ext_vector_type(4)))  float f4v;
typedef __attribute__((ext_vector_type(16))) float f16v;
typedef __attribute__((ext_vector_type(4)))  short s4v;
typedef __attribute__((ext_vector_type(8)))  short s8v;
typedef __attribute__((ext_vector_type(8)))  __bf16 bf8v;
typedef __attribute__((ext_vector_type(2)))  unsigned int u2v;
typedef __attribute__((ext_vector_type(4)))  unsigned int u4v;

// ---------------- ws layout ----------------
// ushort-unit offsets (prep region)
#define WS_AFRAG_US 0          // ushort[1024] : Anorm^T frags [g2:2][lane:64][e:8] (K=16 order)
#define WS_WFRAG_US 1024       // ushort[4096] : W frags      [s2:8][lane:64][e:8] (K=16 order)
// float-unit offsets
#define WS_WF    2560          // float[4096]  : W fp32 [dd:128][k:32] (for k3 ll0)
#define WS_CK    6656          // float[32]
#define WS_AM1   6688          // float[32]
#define WS_BB    6720          // float[32]
#define WS_PI0   6752          // float[32]
#define WS_LS    8192          // float[PCH]   : chunk log-scales
#define WS_LS2   16384         // float[128]   : group log-scales
// short-unit offsets (matrix storage, bf16); lane's 16 ushorts = [old g:4][e:4];
// K=16 frag g2 = shorts 8*g2..8*g2+7 (concat of old K=8 frags 2g2, 2g2+1)
#define SH_MATS  33280                  // ushort[PCH*1024]  : chunk mats
#define SH_MATS2 (33280 + PCH*1024)     // ushort[128*1024]  : group mats
#define LN2F 0.69314718055994531f

__device__ __forceinline__ unsigned pkbf(float hi, float lo) {
    return __builtin_amdgcn_perm(__builtin_bit_cast(unsigned, hi),
                                 __builtin_bit_cast(unsigned, lo), 0x07060302u);
}
__device__ __forceinline__ unsigned short f2bf_rne(float f) {
    unsigned u = __builtin_bit_cast(unsigned, f);
    unsigned r = u + 0x7FFFu + ((u >> 16) & 1u);
    return (unsigned short)(r >> 16);
}
__device__ __forceinline__ float bf2f(unsigned short u) {
    return __builtin_bit_cast(float, (unsigned)u << 16);
}
__device__ __forceinline__ float wmax32(float v) {
    v = fmaxf(v, __shfl_xor(v, 1));  v = fmaxf(v, __shfl_xor(v, 2));
    v = fmaxf(v, __shfl_xor(v, 4));  v = fmaxf(v, __shfl_xor(v, 8));
    v = fmaxf(v, __shfl_xor(v, 16));
    return v;
}
__device__ __forceinline__ float wmax64(float v) {
    v = wmax32(v); v = fmaxf(v, __shfl_xor(v, 32));
    return v;
}
__device__ __forceinline__ float wsum32(float v) {
    v += __shfl_xor(v, 1); v += __shfl_xor(v, 2); v += __shfl_xor(v, 4);
    v += __shfl_xor(v, 8); v += __shfl_xor(v, 16);
    return v;
}
__device__ __forceinline__ float wsum64(float v) {
    v = wsum32(v); v += __shfl_xor(v, 32);
    return v;
}
__device__ __forceinline__ float wval(int dd, int k, const float* mu, const float* lsg) {
    int d = dd & 63;
    float lv = lsg[k * DD + d];
    float iv = __expf(-2.f * lv);
    return (dd < DD) ? (-0.5f * iv) : (mu[k * DD + d] * iv);
}
// gfx950 K=16 bf16 MFMA (full-rate; the _1k K=8 op occupies the same pipe slot for half the FLOPs)
__device__ __forceinline__ f16v mfma16(s8v a, s8v b, f16v c) {
    return __builtin_amdgcn_mfma_f32_32x32x16_bf16(
        __builtin_bit_cast(bf8v, a), __builtin_bit_cast(bf8v, b), c, 0, 0, 0);
}

// ================= k0: constants / fragment preformat =================
__global__ void k0_prep(const float* __restrict__ Y, const float* __restrict__ A,
                        const float* __restrict__ lab, const float* __restrict__ mu,
                        const float* __restrict__ lsg, const float* __restrict__ pi,
                        float* __restrict__ ws, float* __restrict__ out)
{
    __shared__ float lseA[KK];
    const int tid = threadIdx.x;
    if (tid < KK) {
        float m = -1e30f;
        for (int j = 0; j < KK; ++j) m = fmaxf(m, A[tid * KK + j]);
        float s = 0.f;
        for (int j = 0; j < KK; ++j) s += __expf(A[tid * KK + j] - m);
        lseA[tid] = m + __logf(s);

        float mp = -1e30f;
        for (int j = 0; j < KK; ++j) mp = fmaxf(mp, pi[j]);
        float sp = 0.f;
        for (int j = 0; j < KK; ++j) sp += __expf(pi[j] - mp);
        ws[WS_PI0 + tid] = pi[tid] - (mp + __logf(sp));

        float la = lab[tid * 2 + 0], lb = lab[tid * 2 + 1];
        float a = __expf(la), b = __expf(lb);
        float c1 = 0.f, c2 = 0.f;
        for (int d = 0; d < DD; ++d) {
            float lv = lsg[tid * DD + d];
            float mv = mu[tid * DD + d];
            c1 -= lv;
            c2 += mv * mv * __expf(-2.f * lv);
        }
        ws[WS_CK + tid]  = a * lb - lgammaf(a) + c1 - 0.5f * c2 - 32.f * 1.8378770664093453f;
        ws[WS_AM1 + tid] = a - 1.f;
        ws[WS_BB + tid]  = b;
    }
    __syncthreads();
    unsigned short* us = (unsigned short*)ws;
    // A frags, K=16 order: [g2:2][lane:64][e:8]; k = 16*g2 + 8*(e>>2) + 4*h + (e&3)
    for (int idx = tid; idx < 1024; idx += 256) {
        int g2 = idx >> 9, rem = idx & 511, ln = rem >> 3, e = rem & 7;
        int m = 16 * g2 + 8 * (e >> 2) + 4 * (ln >> 5) + (e & 3), i = ln & 31;
        us[WS_AFRAG_US + idx] = f2bf_rne(__expf(A[m * KK + i] - lseA[m]));
    }
    // W frags, K=16 order: [s2:8][lane:64][e:8]; dd = 16*s2 + 8*(e>>2) + 4*h + (e&3)
    // s2 0..3 pair with y^2 (dd 0..63), s2 4..7 pair with y (dd 64..127)
    for (int idx = tid; idx < 4096; idx += 256) {
        int s2 = idx >> 9, rem = idx & 511, ln = rem >> 3, e = rem & 7;
        int dd = 16 * s2 + 8 * (e >> 2) + 4 * (ln >> 5) + (e & 3);
        us[WS_WFRAG_US + idx] = f2bf_rne(wval(dd, ln & 31, mu, lsg));
    }
    for (int idx = tid; idx < 4096; idx += 256) {
        int dd = idx >> 5, k = idx & 31;
        ws[WS_WF + idx] = wval(dd, k, mu, lsg);
    }
    if (tid < DD) out[tid] = Y[tid];   // h row 0
}

// ================= k1: chunk scan (1 wave = 1 chunk of 32 steps) =================
// R5 base (verified 62.2us twice) + three separable edits:
//  (1) wave phase stagger: s_sleep skew (~768cyc * wv) so a block's 4 waves occupy
//      DIFFERENT phases (staging/emission/llphase/scan) and cross-fill pipes --
//      R2-R8 showed phase-locked waves leave every pipe <52% busy.
//  (2) nontemporal h-store: 64MB write never re-read; keep it out of L2.
//  (3) rescale every 8 steps (e<=1, per-row max=1 -> no underflow risk at 8).
__global__ __launch_bounds__(256, 6) void k1_scan(
    const float* __restrict__ Y, const float* __restrict__ dTp,
    float* __restrict__ ws, float* __restrict__ out)
{
    __shared__ __align__(16) float Ebuf[4][1152];        // per-wave: Ybf(4KB) / E(4.5KB) / Tb alias
    __shared__ __align__(16) float dtv[4][32], dtl[4][32];

    const int tid = threadIdx.x;
    const int wv = tid >> 6, l = tid & 63, h = l >> 5, c = l & 31;
    const int p = blockIdx.x * 4 + wv;
    const int t0 = 1 + p * LSTEP;
    const int nsteps = min(LSTEP, TT - t0);

    const unsigned short* afr = (const unsigned short*)ws + WS_AFRAG_US;
    const unsigned short* wfr = (const unsigned short*)ws + WS_WFRAG_US;

    const float cK = ws[WS_CK + c], am1 = ws[WS_AM1 + c], bb = ws[WS_BB + c];

    if (l < 32) {
        int t = t0 + l;
        float dv = (t < TT) ? dTp[t] : 1.f;
        dtv[wv][l] = dv;
        dtl[wv][l] = __logf(dv);
    }

    // ---- (1) de-phase the block's waves: wv * ~768 cycles ----
    for (int sk = 0; sk < wv; ++sk) __builtin_amdgcn_s_sleep(12);

    f16v zf;
    #pragma unroll
    for (int r = 0; r < 16; ++r) zf[r] = 0.f;

    unsigned short* Ybf = (unsigned short*)&Ebuf[wv][0];   // 2048 ushorts, frag order
    float* E = &Ebuf[wv][0];                                // aliases Ybf (Y dead when E written)

    // ---- coalesced Y stage -> LDS bf16 frags, fused coalesced h write ----
    {
        const size_t gbase = (size_t)t0 * DD;
        const int rr = l & 3, cb = l >> 2;
        const int g2s = cb >> 2, bs = (cb >> 1) & 1, hs = cb & 1;
        #pragma unroll
        for (int i = 0; i < 8; ++i) {
            const size_t gi = gbase + (size_t)i * 256 + (size_t)(rr * 64 + cb * 4);
            f4v y4; y4[0] = 0.f; y4[1] = 0.f; y4[2] = 0.f; y4[3] = 0.f;
            const bool ok = gi < (size_t)TT * DD;
            if (ok) y4 = *(const f4v*)(Y + gi);
            if (ok) __builtin_nontemporal_store(y4, (f4v*)(out + gi));   // (2) h never re-read
            const int row = i * 4 + rr;
            const int off = g2s * 512 + (32 * hs + row) * 8 + 4 * bs;   // ushort units, 8B-aligned
            u2v pw; pw[0] = pkbf(y4[1], y4[0]); pw[1] = pkbf(y4[3], y4[2]);
            *(u2v*)(Ybf + off) = pw;
        }
    }
    asm volatile("s_waitcnt lgkmcnt(0)" ::: "memory");  // frag writes visible to own wave

    // ---- emission ll tile via K=16 MFMA; raw-y frag IS the LDS read ----
    f16v acc = zf;
    s8v raws[4];
    #pragma unroll
    for (int g2 = 0; g2 < 4; ++g2) {
        const s8v yf = *(const s8v*)(Ybf + g2 * 512 + l * 8);   // 16B/lane contiguous
        raws[g2] = yf;
        u4v qp;
        #pragma unroll
        for (int e2 = 0; e2 < 4; ++e2) {
            const float f0 = bf2f((unsigned short)yf[2 * e2]);
            const float f1 = bf2f((unsigned short)yf[2 * e2 + 1]);
            qp[e2] = pkbf(f1 * f1, f0 * f0);
        }
        const s8v wf = *(const s8v*)(wfr + g2 * 512 + l * 8);
        acc = mfma16(__builtin_bit_cast(s8v, qp), wf, acc);
    }
    #pragma unroll
    for (int g2 = 0; g2 < 4; ++g2) {
        const s8v wf = *(const s8v*)(wfr + (4 + g2) * 512 + l * 8);
        acc = mfma16(raws[g2], wf, acc);
    }

    // ---- A^T frags (two K=16 groups) ----
    const s8v aF0 = *(const s8v*)(afr + l * 8);
    const s8v aF1 = *(const s8v*)(afr + 512 + l * 8);

    // ---- ll -> c_t (row max over states), e = exp(ll-c) into E (aliases Ybf; Y dead) ----
    float csv = 0.f;
    #pragma unroll
    for (int m = 0; m < 4; ++m) {
        const f4v dv4 = *(const f4v*)(&dtv[wv][8 * m + 4 * h]);
        const f4v dl4 = *(const f4v*)(&dtl[wv][8 * m + 4 * h]);
        #pragma unroll
        for (int j = 0; j < 4; ++j) {
            const int row = 8 * m + 4 * h + j;
            float llv = acc[4 * m + j] + cK + am1 * dl4[j] - bb * dv4[j];
            float cm = wmax32(llv);
            E[row * 36 + c] = __expf(llv - cm);
            csv += (row < nsteps) ? cm : 0.f;
        }
    }
    float cacc = wsum64(csv) * (1.f / 32.f);

    asm volatile("s_waitcnt lgkmcnt(0)" ::: "memory");  // E visible to own wave

    // ---- scan: S <- diag(e_t) * Anorm^T * S ----
    f16v S;
    #pragma unroll
    for (int m = 0; m < 4; ++m)
        #pragma unroll
        for (int j = 0; j < 4; ++j)
            S[4 * m + j] = ((8 * m + 4 * h + j) == c) ? 1.f : 0.f;
    float l2acc = 0.f;

    auto step = [&](int n) {
        u4v b0, b1;
        b0[0] = pkbf(S[1],  S[0]);  b0[1] = pkbf(S[3],  S[2]);
        b0[2] = pkbf(S[5],  S[4]);  b0[3] = pkbf(S[7],  S[6]);
        b1[0] = pkbf(S[9],  S[8]);  b1[1] = pkbf(S[11], S[10]);
        b1[2] = pkbf(S[13], S[12]); b1[3] = pkbf(S[15], S[14]);
        f16v Dv = mfma16(aF0, __builtin_bit_cast(s8v, b0), zf);
        Dv = mfma16(aF1, __builtin_bit_cast(s8v, b1), Dv);
        #pragma unroll
        for (int m = 0; m < 4; ++m) {
            const f4v e4 = *(const f4v*)(E + n * 36 + 8 * m + 4 * h);  // 2-addr broadcast
            S[4 * m + 0] = Dv[4 * m + 0] * e4[0];
            S[4 * m + 1] = Dv[4 * m + 1] * e4[1];
            S[4 * m + 2] = Dv[4 * m + 2] * e4[2];
            S[4 * m + 3] = Dv[4 * m + 3] * e4[3];
        }
    };
    auto rescale = [&]() {
        float mx = S[0];
        #pragma unroll
        for (int r = 1; r < 16; ++r) mx = fmaxf(mx, S[r]);
        mx = wmax64(mx);
        const float inv = __fdividef(1.f, mx);
        #pragma unroll
        for (int r = 0; r < 16; ++r) S[r] *= inv;
        l2acc += __log2f(mx);
    };

    if (p != PCH - 1) {
        #pragma unroll
        for (int n = 0; n < LSTEP; ++n) {
            step(n);
            if ((n & 7) == 7) rescale();     // (3) every-8: e<=1, row max=1 -> safe
        }
    } else {
        for (int n = 0; n < nsteps; ++n) {
            step(n);
            if ((n & 7) == 7) rescale();
        }
    }

    // ---- transpose S (C-layout) -> frag order bf16, coalesced store ----
    unsigned short* Tb = (unsigned short*)&Ebuf[wv][0];    // E is dead now
    asm volatile("s_waitcnt lgkmcnt(0)" ::: "memory");
    #pragma unroll
    for (int m = 0; m < 4; ++m)
        #pragma unroll
        for (int j = 0; j < 4; ++j)
            Tb[(8 * m + 4 * h + j) * 36 + c] = f2bf_rne(S[4 * m + j]);
    asm volatile("s_waitcnt lgkmcnt(0)" ::: "memory");
    u2v tg0 = *(const u2v*)(Tb + c * 36 + 0  + 4 * h);
    u2v tg1 = *(const u2v*)(Tb + c * 36 + 8  + 4 * h);
    u2v tg2 = *(const u2v*)(Tb + c * 36 + 16 + 4 * h);
    u2v tg3 = *(const u2v*)(Tb + c * 36 + 24 + 4 * h);
    unsigned short* gm = (unsigned short*)ws + SH_MATS + (size_t)p * 1024 + l * 16;
    u4v s0; s0[0] = tg0[0]; s0[1] = tg0[1]; s0[2] = tg1[0]; s0[3] = tg1[1];
    u4v s1; s1[0] = tg2[0]; s1[1] = tg2[1]; s1[2] = tg3[0]; s1[3] = tg3[1];
    *(u4v*)(gm) = s0;
    *(u4v*)(gm + 8) = s1;
    if (l == 0) ws[WS_LS + p] = cacc + LN2F * l2acc;
}

// ---- helper: one product step  U <- A_mat * U  (A from 2 uint4 regs = two K=16 frags) ----
__device__ __forceinline__ f16v prodAU(const u4v a0, const u4v a1, const f16v U, const f16v zf) {
    u4v b0, b1;
    b0[0] = pkbf(U[1],  U[0]);  b0[1] = pkbf(U[3],  U[2]);
    b0[2] = pkbf(U[5],  U[4]);  b0[3] = pkbf(U[7],  U[6]);
    b1[0] = pkbf(U[9],  U[8]);  b1[1] = pkbf(U[11], U[10]);
    b1[2] = pkbf(U[13], U[12]); b1[3] = pkbf(U[15], U[14]);
    f16v Dv = mfma16(__builtin_bit_cast(s8v, a0), __builtin_bit_cast(s8v, b0), zf);
    Dv = mfma16(__builtin_bit_cast(s8v, a1), __builtin_bit_cast(s8v, b1), Dv);
    return Dv;
}

// ================= k2: combine 64 chunk mats per block (2 waves x 32 + pair) =================
__global__ __launch_bounds__(128, 1) void k2_combine(float* __restrict__ ws)
{
    __shared__ __align__(16) unsigned short slot[2][1152];  // row-major, stride 36
    __shared__ float scl[2], lac[2];
    const int tid = threadIdx.x, wv = tid >> 6, l = tid & 63, h = l >> 5, c = l & 31;
    const int blk = blockIdx.x;
    const int idx0 = blk * 64 + wv * 32;
    const unsigned short* mats = (const unsigned short*)ws + SH_MATS;

    float lsv = (l < 32) ? ws[WS_LS + idx0 + l] : 0.f;
    float lssum = wsum64(lsv);

    f16v zf;
    #pragma unroll
    for (int r = 0; r < 16; ++r) zf[r] = 0.f;
    f16v U;
    #pragma unroll
    for (int m = 0; m < 4; ++m)
        #pragma unroll
        for (int j = 0; j < 4; ++j)
            U[4 * m + j] = ((8 * m + 4 * h + j) == c) ? 1.f : 0.f;
    float l2a = 0.f;

    u4v pf[2][2];
    {
        const u4v* mp0 = (const u4v*)(mats + (size_t)idx0 * 1024) + l * 2;
        const u4v* mp1 = (const u4v*)(mats + (size_t)(idx0 + 1) * 1024) + l * 2;
        pf[0][0] = mp0[0]; pf[0][1] = mp0[1];
        pf[1][0] = mp1[0]; pf[1][1] = mp1[1];
    }
    for (int q = 0; q < 32; ++q) {
        const u4v a0 = pf[q & 1][0], a1 = pf[q & 1][1];
        if (q + 2 < 32) {
            const u4v* mp = (const u4v*)(mats + (size_t)(idx0 + q + 2) * 1024) + l * 2;
            pf[q & 1][0] = mp[0]; pf[q & 1][1] = mp[1];
        }
        f16v Dv = prodAU(a0, a1, U, zf);
        if ((q & 3) == 3) {
            float mx = Dv[0];
            #pragma unroll
            for (int r = 1; r < 16; ++r) mx = fmaxf(mx, Dv[r]);
            mx = wmax64(mx);
            const float inv = __fdividef(1.f, mx);
            #pragma unroll
            for (int r = 0; r < 16; ++r) U[r] = Dv[r] * inv;
            l2a += __log2f(mx);
        } else {
            U = Dv;
        }
    }
    #pragma unroll
    for (int m = 0; m < 4; ++m)
        #pragma unroll
        for (int j = 0; j < 4; ++j)
            slot[wv][(8 * m + 4 * h + j) * 36 + c] = f2bf_rne(U[4 * m + j]);
    if (l == 0) { scl[wv] = lssum; lac[wv] = l2a; }
    __syncthreads();

    if (wv == 0) {
        u4v a0, a1;
        {
            u2v t0 = *(const u2v*)(&slot[1][c * 36 + 0 + 4 * h]);
            u2v t1 = *(const u2v*)(&slot[1][c * 36 + 8 + 4 * h]);
            u2v t2 = *(const u2v*)(&slot[1][c * 36 + 16 + 4 * h]);
            u2v t3 = *(const u2v*)(&slot[1][c * 36 + 24 + 4 * h]);
            a0[0] = t0[0]; a0[1] = t0[1]; a0[2] = t1[0]; a0[3] = t1[1];
            a1[0] = t2[0]; a1[1] = t2[1]; a1[2] = t3[0]; a1[3] = t3[1];
        }
        f16v Dv = prodAU(a0, a1, U, zf);
        float mx = Dv[0];
        #pragma unroll
        for (int r = 1; r < 16; ++r) mx = fmaxf(mx, Dv[r]);
        mx = wmax64(mx);
        const float inv = __fdividef(1.f, mx);
        #pragma unroll
        for (int r = 0; r < 16; ++r) U[r] = Dv[r] * inv;
        const float l2tot = lac[0] + lac[1] + __log2f(mx);
        asm volatile("s_waitcnt lgkmcnt(0)" ::: "memory");
        #pragma unroll
        for (int m = 0; m < 4; ++m)
            #pragma unroll
            for (int j = 0; j < 4; ++j)
                slot[0][(8 * m + 4 * h + j) * 36 + c] = f2bf_rne(U[4 * m + j]);
        asm volatile("s_waitcnt lgkmcnt(0)" ::: "memory");
        u2v tg[4];
        #pragma unroll
        for (int g = 0; g < 4; ++g)
            tg[g] = *(const u2v*)(&slot[0][c * 36 + 8 * g + 4 * h]);
        unsigned short* gm = (unsigned short*)ws + SH_MATS2 + (size_t)blk * 1024 + l * 16;
        u4v s0; s0[0] = tg[0][0]; s0[1] = tg[0][1]; s0[2] = tg[1][0]; s0[3] = tg[1][1];
        u4v s1; s1[0] = tg[2][0]; s1[1] = tg[2][1]; s1[2] = tg[3][0]; s1[3] = tg[3][1];
        *(u4v*)(gm) = s0;
        *(u4v*)(gm + 8) = s1;
        if (l == 0) ws[WS_LS2 + blk] = scl[0] + scl[1] + LN2F * l2tot;
    }
}

// ================= k3: 16 chains of 8 + LDS tree + final loss =================
__global__ __launch_bounds__(1024, 1) void k3_final(
    const float* __restrict__ Y, const float* __restrict__ dTp,
    float* __restrict__ ws, float* __restrict__ out)
{
    __shared__ __align__(16) unsigned short slot[16][1152];
    __shared__ float sc[16];
    const int tid = threadIdx.x, wv = tid >> 6, l = tid & 63, h = l >> 5, c = l & 31;
    const unsigned short* mats2 = (const unsigned short*)ws + SH_MATS2;

    f16v zf;
    #pragma unroll
    for (int r = 0; r < 16; ++r) zf[r] = 0.f;

    const int idx0 = wv * 8;
    float lsv = (l < 8) ? ws[WS_LS2 + idx0 + l] : 0.f;
    float lssum = wsum64(lsv);
    f16v U;
    #pragma unroll
    for (int m = 0; m < 4; ++m)
        #pragma unroll
        for (int j = 0; j < 4; ++j)
            U[4 * m + j] = ((8 * m + 4 * h + j) == c) ? 1.f : 0.f;
    float l2a = 0.f;
    u4v pf[2][2];
    {
        const u4v* mp0 = (const u4v*)(mats2 + (size_t)idx0 * 1024) + l * 2;
        const u4v* mp1 = (const u4v*)(mats2 + (size_t)(idx0 + 1) * 1024) + l * 2;
        pf[0][0] = mp0[0]; pf[0][1] = mp0[1];
        pf[1][0] = mp1[0]; pf[1][1] = mp1[1];
    }
    for (int q = 0; q < 8; ++q) {
        const u4v a0 = pf[q & 1][0], a1 = pf[q & 1][1];
        if (q + 2 < 8) {
            const u4v* mp = (const u4v*)(mats2 + (size_t)(idx0 + q + 2) * 1024) + l * 2;
            pf[q & 1][0] = mp[0]; pf[q & 1][1] = mp[1];
        }
        f16v Dv = prodAU(a0, a1, U, zf);
        if ((q & 3) == 3) {
            float mx = Dv[0];
            #pragma unroll
            for (int r = 1; r < 16; ++r) mx = fmaxf(mx, Dv[r]);
            mx = wmax64(mx);
            const float inv = __fdividef(1.f, mx);
            #pragma unroll
            for (int r = 0; r < 16; ++r) U[r] = Dv[r] * inv;
            l2a += __log2f(mx);
        } else {
            U = Dv;
        }
    }
    #pragma unroll
    for (int m = 0; m < 4; ++m)
        #pragma unroll
        for (int j = 0; j < 4; ++j)
            slot[wv][(8 * m + 4 * h + j) * 36 + c] = f2bf_rne(U[4 * m + j]);
    if (l == 0) sc[wv] = lssum + LN2F * l2a;
    __syncthreads();

    for (int s = 1; s < 16; s <<= 1) {
        const int cnt = 16 / (2 * s);
        if (wv < cnt) {
            const int i = wv * 2 * s;
            s8v aA0, aA1, bB0, bB1;
            {
                u2v t0 = *(const u2v*)(&slot[i + s][c * 36 + 0 + 4 * h]);
                u2v t1 = *(const u2v*)(&slot[i + s][c * 36 + 8 + 4 * h]);
                u2v t2 = *(const u2v*)(&slot[i + s][c * 36 + 16 + 4 * h]);
                u2v t3 = *(const u2v*)(&slot[i + s][c * 36 + 24 + 4 * h]);
                u4v a0; a0[0] = t0[0]; a0[1] = t0[1]; a0[2] = t1[0]; a0[3] = t1[1];
                u4v a1; a1[0] = t2[0]; a1[1] = t2[1]; a1[2] = t3[0]; a1[3] = t3[1];
                aA0 = __builtin_bit_cast(s8v, a0);
                aA1 = __builtin_bit_cast(s8v, a1);
                #pragma unroll
                for (int j = 0; j < 4; ++j) {
                    bB0[j]     = (short)slot[i][(0  + 4 * h + j) * 36 + c];
                    bB0[4 + j] = (short)slot[i][(8  + 4 * h + j) * 36 + c];
                    bB1[j]     = (short)slot[i][(16 + 4 * h + j) * 36 + c];
                    bB1[4 + j] = (short)slot[i][(24 + 4 * h + j) * 36 + c];
                }
            }
            f16v Dv = mfma16(aA0, bB0, zf);
            Dv = mfma16(aA1, bB1, Dv);
            float mx = Dv[0];
            #pragma unroll
            for (int r = 1; r < 16; ++r) mx = fmaxf(mx, Dv[r]);
            mx = wmax64(mx);
            const float inv = __fdividef(1.f, mx);
            #pragma unroll
            for (int m = 0; m < 4; ++m)
                #pragma unroll
                for (int j = 0; j < 4; ++j)
                    slot[i][(8 * m + 4 * h + j) * 36 + c] = f2bf_rne(Dv[4 * m + j] * inv);
            if (l == 0) sc[i] = sc[i] + sc[i + s] + __logf(mx);
        }
        __syncthreads();
    }

    if (wv == 0) {
        float acc = 0.f;
        const float* Wf = ws + WS_WF;
        for (int dd = 0; dd < 128; ++dd) {
            const float yv = Y[dd & 63];
            const float f = (dd < 64) ? yv * yv : yv;
            acc = fmaf(f, Wf[dd * 32 + c], acc);
        }
        const float dt0 = dTp[0];
        const float ll0 = acc + ws[WS_CK + c] + ws[WS_AM1 + c] * __logf(dt0) - ws[WS_BB + c] * dt0;
        const float av = ws[WS_PI0 + c] + ll0;
        const float c0 = wmax32(av);
        const float a0 = __expf(av - c0);
        float part = 0.f;
        #pragma unroll
        for (int i = 0; i < 16; ++i) {
            const int ii = 16 * h + i;
            const float m = bf2f(slot[0][c * 36 + ii]);
            const float ai = __shfl(a0, ii);
            part = fmaf(m, ai, part);
        }
        const float srow = part + __shfl_xor(part, 32);
        const float tot = wsum32(srow);
        if (l == 0) out[(size_t)TT * DD] = -(sc[0] + c0 + __logf(tot));
    }
}

// ================= launcher =================
extern "C" void kernel_launch(void* const* d_in, const int* in_sizes, int n_in,
                              void* d_out, int out_size, void* d_ws, size_t ws_size,
                              hipStream_t stream)
{
    const float* Y   = (const float*)d_in[0];
    const float* dTp = (const float*)d_in[1];
    const float* A   = (const float*)d_in[2];
    const float* lab = (const float*)d_in[3];
    const float* mu  = (const float*)d_in[4];
    const float* lsg = (const float*)d_in[5];
    const float* pi  = (const float*)d_in[6];
    float* out = (float*)d_out;
    float* ws  = (float*)d_ws;

    hipLaunchKernelGGL(k0_prep, dim3(1), dim3(256), 0, stream, Y, A, lab, mu, lsg, pi, ws, out);
    hipLaunchKernelGGL(k1_scan, dim3(PCH / 4), dim3(256), 0, stream, Y, dTp, ws, out);
    hipLaunchKernelGGL(k2_combine, dim3(128), dim3(128), 0, stream, ws);
    hipLaunchKernelGGL(k3_final, dim3(1), dim3(1024), 0, stream, Y, dTp, ws, out);
}

// Round 10
// 185.376 us; speedup vs baseline: 1.0484x; 1.0257x over previous
//
#include <hip/hip_runtime.h>
#include <stdint.h>

// ---------------- problem constants ----------------
#define TT 262144
#define KK 32
#define DD 64
#define LSTEP 32               // scan steps per chunk
#define PCH 8192               // chunks (transitions t=1..T-1; last chunk has 31 steps)

typedef __attribute__((ext_vector_type(4)))  float f4v;
typedef __attribute__((ext_vector_type(16))) float f16v;
typedef __attribute__((ext_vector_type(4)))  short s4v;
typedef __attribute__((ext_vector_type(8)))  short s8v;
typedef __attribute__((ext_vector_type(8)))  __bf16 bf8v;
typedef __attribute__((ext_vector_type(2)))  unsigned int u2v;
typedef __attribute__((ext_vector_type(4)))  unsigned int u4v;

// ---------------- ws layout ----------------
// ushort-unit offsets (prep region)
#define WS_AFRAG_US 0          // ushort[1024] : Anorm^T frags [g2:2][lane:64][e:8] (K=16 order)
#define WS_WFRAG_US 1024       // ushort[4096] : W frags      [s2:8][lane:64][e:8] (K=16 order)
// float-unit offsets
#define WS_WF    2560          // float[4096]  : W fp32 [dd:128][k:32] (for k3 ll0)
#define WS_CK    6656          // float[32]
#define WS_AM1   6688          // float[32]
#define WS_BB    6720          // float[32]
#define WS_PI0   6752          // float[32]
#define WS_LS    8192          // float[PCH]   : chunk log-scales
#define WS_LS2   16384         // float[128]   : group log-scales
// short-unit offsets (matrix storage, bf16); lane's 16 ushorts = [old g:4][e:4];
// K=16 frag g2 = shorts 8*g2..8*g2+7 (concat of old K=8 frags 2g2, 2g2+1)
#define SH_MATS  33280                  // ushort[PCH*1024]  : chunk mats
#define SH_MATS2 (33280 + PCH*1024)     // ushort[128*1024]  : group mats
#define LN2F 0.69314718055994531f

__device__ __forceinline__ unsigned pkbf(float hi, float lo) {
    return __builtin_amdgcn_perm(__builtin_bit_cast(unsigned, hi),
                                 __builtin_bit_cast(unsigned, lo), 0x07060302u);
}
__device__ __forceinline__ unsigned short f2bf_rne(float f) {
    unsigned u = __builtin_bit_cast(unsigned, f);
    unsigned r = u + 0x7FFFu + ((u >> 16) & 1u);
    return (unsigned short)(r >> 16);
}
__device__ __forceinline__ float bf2f(unsigned short u) {
    return __builtin_bit_cast(float, (unsigned)u << 16);
}
__device__ __forceinline__ float wmax32(float v) {
    v = fmaxf(v, __shfl_xor(v, 1));  v = fmaxf(v, __shfl_xor(v, 2));
    v = fmaxf(v, __shfl_xor(v, 4));  v = fmaxf(v, __shfl_xor(v, 8));
    v = fmaxf(v, __shfl_xor(v, 16));
    return v;
}
__device__ __forceinline__ float wmax64(float v) {
    v = wmax32(v); v = fmaxf(v, __shfl_xor(v, 32));
    return v;
}
__device__ __forceinline__ float wsum32(float v) {
    v += __shfl_xor(v, 1); v += __shfl_xor(v, 2); v += __shfl_xor(v, 4);
    v += __shfl_xor(v, 8); v += __shfl_xor(v, 16);
    return v;
}
__device__ __forceinline__ float wsum64(float v) {
    v = wsum32(v); v += __shfl_xor(v, 32);
    return v;
}
__device__ __forceinline__ float wval(int dd, int k, const float* mu, const float* lsg) {
    int d = dd & 63;
    float lv = lsg[k * DD + d];
    float iv = __expf(-2.f * lv);
    return (dd < DD) ? (-0.5f * iv) : (mu[k * DD + d] * iv);
}
// gfx950 K=16 bf16 MFMA (full-rate; the _1k K=8 op occupies the same pipe slot for half the FLOPs)
__device__ __forceinline__ f16v mfma16(s8v a, s8v b, f16v c) {
    return __builtin_amdgcn_mfma_f32_32x32x16_bf16(
        __builtin_bit_cast(bf8v, a), __builtin_bit_cast(bf8v, b), c, 0, 0, 0);
}

// ================= k0: constants / fragment preformat =================
__global__ void k0_prep(const float* __restrict__ Y, const float* __restrict__ A,
                        const float* __restrict__ lab, const float* __restrict__ mu,
                        const float* __restrict__ lsg, const float* __restrict__ pi,
                        float* __restrict__ ws, float* __restrict__ out)
{
    __shared__ float lseA[KK];
    const int tid = threadIdx.x;
    if (tid < KK) {
        float m = -1e30f;
        for (int j = 0; j < KK; ++j) m = fmaxf(m, A[tid * KK + j]);
        float s = 0.f;
        for (int j = 0; j < KK; ++j) s += __expf(A[tid * KK + j] - m);
        lseA[tid] = m + __logf(s);

        float mp = -1e30f;
        for (int j = 0; j < KK; ++j) mp = fmaxf(mp, pi[j]);
        float sp = 0.f;
        for (int j = 0; j < KK; ++j) sp += __expf(pi[j] - mp);
        ws[WS_PI0 + tid] = pi[tid] - (mp + __logf(sp));

        float la = lab[tid * 2 + 0], lb = lab[tid * 2 + 1];
        float a = __expf(la), b = __expf(lb);
        float c1 = 0.f, c2 = 0.f;
        for (int d = 0; d < DD; ++d) {
            float lv = lsg[tid * DD + d];
            float mv = mu[tid * DD + d];
            c1 -= lv;
            c2 += mv * mv * __expf(-2.f * lv);
        }
        ws[WS_CK + tid]  = a * lb - lgammaf(a) + c1 - 0.5f * c2 - 32.f * 1.8378770664093453f;
        ws[WS_AM1 + tid] = a - 1.f;
        ws[WS_BB + tid]  = b;
    }
    __syncthreads();
    unsigned short* us = (unsigned short*)ws;
    // A frags, K=16 order: [g2:2][lane:64][e:8]; k = 16*g2 + 8*(e>>2) + 4*h + (e&3)
    for (int idx = tid; idx < 1024; idx += 256) {
        int g2 = idx >> 9, rem = idx & 511, ln = rem >> 3, e = rem & 7;
        int m = 16 * g2 + 8 * (e >> 2) + 4 * (ln >> 5) + (e & 3), i = ln & 31;
        us[WS_AFRAG_US + idx] = f2bf_rne(__expf(A[m * KK + i] - lseA[m]));
    }
    // W frags, K=16 order: [s2:8][lane:64][e:8]; dd = 16*s2 + 8*(e>>2) + 4*h + (e&3)
    // s2 0..3 pair with y^2 (dd 0..63), s2 4..7 pair with y (dd 64..127)
    for (int idx = tid; idx < 4096; idx += 256) {
        int s2 = idx >> 9, rem = idx & 511, ln = rem >> 3, e = rem & 7;
        int dd = 16 * s2 + 8 * (e >> 2) + 4 * (ln >> 5) + (e & 3);
        us[WS_WFRAG_US + idx] = f2bf_rne(wval(dd, ln & 31, mu, lsg));
    }
    for (int idx = tid; idx < 4096; idx += 256) {
        int dd = idx >> 5, k = idx & 31;
        ws[WS_WF + idx] = wval(dd, k, mu, lsg);
    }
    if (tid < DD) out[tid] = Y[tid];   // h row 0
}

// ================= k1: chunk scan (1 wave = 1 chunk of 32 steps) =================
// R5 base (verified 62.2us twice: bf16 Y-frag staging with fused coalesced h write,
// f32 E stride-36 aliasing dead Y, shfl reductions, 19456B LDS -> high occupancy)
// + ONE isolated edit: rescale every 8 steps instead of 4 (R9 showed it cuts VALU
// busy-time 24.6->22us; R9's other two edits masked the dur effect). Correctness of
// every-8 verified by R9's pass (e<=1, per-row max=1; bf16 exponent range = f32's).
__global__ __launch_bounds__(256, 6) void k1_scan(
    const float* __restrict__ Y, const float* __restrict__ dTp,
    float* __restrict__ ws, float* __restrict__ out)
{
    __shared__ __align__(16) float Ebuf[4][1152];        // per-wave: Ybf(4KB) / E(4.5KB) / Tb alias
    __shared__ __align__(16) float dtv[4][32], dtl[4][32];

    const int tid = threadIdx.x;
    const int wv = tid >> 6, l = tid & 63, h = l >> 5, c = l & 31;
    const int p = blockIdx.x * 4 + wv;
    const int t0 = 1 + p * LSTEP;
    const int nsteps = min(LSTEP, TT - t0);

    const unsigned short* afr = (const unsigned short*)ws + WS_AFRAG_US;
    const unsigned short* wfr = (const unsigned short*)ws + WS_WFRAG_US;

    const float cK = ws[WS_CK + c], am1 = ws[WS_AM1 + c], bb = ws[WS_BB + c];

    if (l < 32) {
        int t = t0 + l;
        float dv = (t < TT) ? dTp[t] : 1.f;
        dtv[wv][l] = dv;
        dtl[wv][l] = __logf(dv);
    }

    f16v zf;
    #pragma unroll
    for (int r = 0; r < 16; ++r) zf[r] = 0.f;

    unsigned short* Ybf = (unsigned short*)&Ebuf[wv][0];   // 2048 ushorts, frag order
    float* E = &Ebuf[wv][0];                                // aliases Ybf (Y dead when E written)

    // ---- coalesced Y stage -> LDS bf16 frags, fused coalesced h write ----
    {
        const size_t gbase = (size_t)t0 * DD;
        const int rr = l & 3, cb = l >> 2;
        const int g2s = cb >> 2, bs = (cb >> 1) & 1, hs = cb & 1;
        #pragma unroll
        for (int i = 0; i < 8; ++i) {
            const size_t gi = gbase + (size_t)i * 256 + (size_t)(rr * 64 + cb * 4);
            f4v y4; y4[0] = 0.f; y4[1] = 0.f; y4[2] = 0.f; y4[3] = 0.f;
            const bool ok = gi < (size_t)TT * DD;
            if (ok) y4 = *(const f4v*)(Y + gi);
            if (ok) *(f4v*)(out + gi) = y4;
            const int row = i * 4 + rr;
            const int off = g2s * 512 + (32 * hs + row) * 8 + 4 * bs;   // ushort units, 8B-aligned
            u2v pw; pw[0] = pkbf(y4[1], y4[0]); pw[1] = pkbf(y4[3], y4[2]);
            *(u2v*)(Ybf + off) = pw;
        }
    }
    asm volatile("s_waitcnt lgkmcnt(0)" ::: "memory");  // frag writes visible to own wave

    // ---- emission ll tile via K=16 MFMA; raw-y frag IS the LDS read ----
    f16v acc = zf;
    s8v raws[4];
    #pragma unroll
    for (int g2 = 0; g2 < 4; ++g2) {
        const s8v yf = *(const s8v*)(Ybf + g2 * 512 + l * 8);   // 16B/lane contiguous
        raws[g2] = yf;
        u4v qp;
        #pragma unroll
        for (int e2 = 0; e2 < 4; ++e2) {
            const float f0 = bf2f((unsigned short)yf[2 * e2]);
            const float f1 = bf2f((unsigned short)yf[2 * e2 + 1]);
            qp[e2] = pkbf(f1 * f1, f0 * f0);
        }
        const s8v wf = *(const s8v*)(wfr + g2 * 512 + l * 8);
        acc = mfma16(__builtin_bit_cast(s8v, qp), wf, acc);
    }
    #pragma unroll
    for (int g2 = 0; g2 < 4; ++g2) {
        const s8v wf = *(const s8v*)(wfr + (4 + g2) * 512 + l * 8);
        acc = mfma16(raws[g2], wf, acc);
    }

    // ---- A^T frags (two K=16 groups) ----
    const s8v aF0 = *(const s8v*)(afr + l * 8);
    const s8v aF1 = *(const s8v*)(afr + 512 + l * 8);

    // ---- ll -> c_t (row max over states), e = exp(ll-c) into E (aliases Ybf; Y dead) ----
    float csv = 0.f;
    #pragma unroll
    for (int m = 0; m < 4; ++m) {
        const f4v dv4 = *(const f4v*)(&dtv[wv][8 * m + 4 * h]);
        const f4v dl4 = *(const f4v*)(&dtl[wv][8 * m + 4 * h]);
        #pragma unroll
        for (int j = 0; j < 4; ++j) {
            const int row = 8 * m + 4 * h + j;
            float llv = acc[4 * m + j] + cK + am1 * dl4[j] - bb * dv4[j];
            float cm = wmax32(llv);
            E[row * 36 + c] = __expf(llv - cm);
            csv += (row < nsteps) ? cm : 0.f;
        }
    }
    float cacc = wsum64(csv) * (1.f / 32.f);

    asm volatile("s_waitcnt lgkmcnt(0)" ::: "memory");  // E visible to own wave

    // ---- scan: S <- diag(e_t) * Anorm^T * S ----
    f16v S;
    #pragma unroll
    for (int m = 0; m < 4; ++m)
        #pragma unroll
        for (int j = 0; j < 4; ++j)
            S[4 * m + j] = ((8 * m + 4 * h + j) == c) ? 1.f : 0.f;
    float l2acc = 0.f;

    auto step = [&](int n) {
        u4v b0, b1;
        b0[0] = pkbf(S[1],  S[0]);  b0[1] = pkbf(S[3],  S[2]);
        b0[2] = pkbf(S[5],  S[4]);  b0[3] = pkbf(S[7],  S[6]);
        b1[0] = pkbf(S[9],  S[8]);  b1[1] = pkbf(S[11], S[10]);
        b1[2] = pkbf(S[13], S[12]); b1[3] = pkbf(S[15], S[14]);
        f16v Dv = mfma16(aF0, __builtin_bit_cast(s8v, b0), zf);
        Dv = mfma16(aF1, __builtin_bit_cast(s8v, b1), Dv);
        #pragma unroll
        for (int m = 0; m < 4; ++m) {
            const f4v e4 = *(const f4v*)(E + n * 36 + 8 * m + 4 * h);  // 2-addr broadcast
            S[4 * m + 0] = Dv[4 * m + 0] * e4[0];
            S[4 * m + 1] = Dv[4 * m + 1] * e4[1];
            S[4 * m + 2] = Dv[4 * m + 2] * e4[2];
            S[4 * m + 3] = Dv[4 * m + 3] * e4[3];
        }
    };
    auto rescale = [&]() {
        float mx = S[0];
        #pragma unroll
        for (int r = 1; r < 16; ++r) mx = fmaxf(mx, S[r]);
        mx = wmax64(mx);
        const float inv = __fdividef(1.f, mx);
        #pragma unroll
        for (int r = 0; r < 16; ++r) S[r] *= inv;
        l2acc += __log2f(mx);
    };

    if (p != PCH - 1) {
        #pragma unroll
        for (int n = 0; n < LSTEP; ++n) {
            step(n);
            if ((n & 7) == 7) rescale();     // every-8: e<=1, per-row max=1 -> safe (R9-verified)
        }
    } else {
        for (int n = 0; n < nsteps; ++n) {
            step(n);
            if ((n & 7) == 7) rescale();
        }
    }

    // ---- transpose S (C-layout) -> frag order bf16, coalesced store ----
    unsigned short* Tb = (unsigned short*)&Ebuf[wv][0];    // E is dead now
    asm volatile("s_waitcnt lgkmcnt(0)" ::: "memory");
    #pragma unroll
    for (int m = 0; m < 4; ++m)
        #pragma unroll
        for (int j = 0; j < 4; ++j)
            Tb[(8 * m + 4 * h + j) * 36 + c] = f2bf_rne(S[4 * m + j]);
    asm volatile("s_waitcnt lgkmcnt(0)" ::: "memory");
    u2v tg0 = *(const u2v*)(Tb + c * 36 + 0  + 4 * h);
    u2v tg1 = *(const u2v*)(Tb + c * 36 + 8  + 4 * h);
    u2v tg2 = *(const u2v*)(Tb + c * 36 + 16 + 4 * h);
    u2v tg3 = *(const u2v*)(Tb + c * 36 + 24 + 4 * h);
    unsigned short* gm = (unsigned short*)ws + SH_MATS + (size_t)p * 1024 + l * 16;
    u4v s0; s0[0] = tg0[0]; s0[1] = tg0[1]; s0[2] = tg1[0]; s0[3] = tg1[1];
    u4v s1; s1[0] = tg2[0]; s1[1] = tg2[1]; s1[2] = tg3[0]; s1[3] = tg3[1];
    *(u4v*)(gm) = s0;
    *(u4v*)(gm + 8) = s1;
    if (l == 0) ws[WS_LS + p] = cacc + LN2F * l2acc;
}

// ---- helper: one product step  U <- A_mat * U  (A from 2 uint4 regs = two K=16 frags) ----
__device__ __forceinline__ f16v prodAU(const u4v a0, const u4v a1, const f16v U, const f16v zf) {
    u4v b0, b1;
    b0[0] = pkbf(U[1],  U[0]);  b0[1] = pkbf(U[3],  U[2]);
    b0[2] = pkbf(U[5],  U[4]);  b0[3] = pkbf(U[7],  U[6]);
    b1[0] = pkbf(U[9],  U[8]);  b1[1] = pkbf(U[11], U[10]);
    b1[2] = pkbf(U[13], U[12]); b1[3] = pkbf(U[15], U[14]);
    f16v Dv = mfma16(__builtin_bit_cast(s8v, a0), __builtin_bit_cast(s8v, b0), zf);
    Dv = mfma16(__builtin_bit_cast(s8v, a1), __builtin_bit_cast(s8v, b1), Dv);
    return Dv;
}

// ================= k2: combine 64 chunk mats per block (2 waves x 32 + pair) =================
__global__ __launch_bounds__(128, 1) void k2_combine(float* __restrict__ ws)
{
    __shared__ __align__(16) unsigned short slot[2][1152];  // row-major, stride 36
    __shared__ float scl[2], lac[2];
    const int tid = threadIdx.x, wv = tid >> 6, l = tid & 63, h = l >> 5, c = l & 31;
    const int blk = blockIdx.x;
    const int idx0 = blk * 64 + wv * 32;
    const unsigned short* mats = (const unsigned short*)ws + SH_MATS;

    float lsv = (l < 32) ? ws[WS_LS + idx0 + l] : 0.f;
    float lssum = wsum64(lsv);

    f16v zf;
    #pragma unroll
    for (int r = 0; r < 16; ++r) zf[r] = 0.f;
    f16v U;
    #pragma unroll
    for (int m = 0; m < 4; ++m)
        #pragma unroll
        for (int j = 0; j < 4; ++j)
            U[4 * m + j] = ((8 * m + 4 * h + j) == c) ? 1.f : 0.f;
    float l2a = 0.f;

    u4v pf[2][2];
    {
        const u4v* mp0 = (const u4v*)(mats + (size_t)idx0 * 1024) + l * 2;
        const u4v* mp1 = (const u4v*)(mats + (size_t)(idx0 + 1) * 1024) + l * 2;
        pf[0][0] = mp0[0]; pf[0][1] = mp0[1];
        pf[1][0] = mp1[0]; pf[1][1] = mp1[1];
    }
    for (int q = 0; q < 32; ++q) {
        const u4v a0 = pf[q & 1][0], a1 = pf[q & 1][1];
        if (q + 2 < 32) {
            const u4v* mp = (const u4v*)(mats + (size_t)(idx0 + q + 2) * 1024) + l * 2;
            pf[q & 1][0] = mp[0]; pf[q & 1][1] = mp[1];
        }
        f16v Dv = prodAU(a0, a1, U, zf);
        if ((q & 3) == 3) {
            float mx = Dv[0];
            #pragma unroll
            for (int r = 1; r < 16; ++r) mx = fmaxf(mx, Dv[r]);
            mx = wmax64(mx);
            const float inv = __fdividef(1.f, mx);
            #pragma unroll
            for (int r = 0; r < 16; ++r) U[r] = Dv[r] * inv;
            l2a += __log2f(mx);
        } else {
            U = Dv;
        }
    }
    #pragma unroll
    for (int m = 0; m < 4; ++m)
        #pragma unroll
        for (int j = 0; j < 4; ++j)
            slot[wv][(8 * m + 4 * h + j) * 36 + c] = f2bf_rne(U[4 * m + j]);
    if (l == 0) { scl[wv] = lssum; lac[wv] = l2a; }
    __syncthreads();

    if (wv == 0) {
        u4v a0, a1;
        {
            u2v t0 = *(const u2v*)(&slot[1][c * 36 + 0 + 4 * h]);
            u2v t1 = *(const u2v*)(&slot[1][c * 36 + 8 + 4 * h]);
            u2v t2 = *(const u2v*)(&slot[1][c * 36 + 16 + 4 * h]);
            u2v t3 = *(const u2v*)(&slot[1][c * 36 + 24 + 4 * h]);
            a0[0] = t0[0]; a0[1] = t0[1]; a0[2] = t1[0]; a0[3] = t1[1];
            a1[0] = t2[0]; a1[1] = t2[1]; a1[2] = t3[0]; a1[3] = t3[1];
        }
        f16v Dv = prodAU(a0, a1, U, zf);
        float mx = Dv[0];
        #pragma unroll
        for (int r = 1; r < 16; ++r) mx = fmaxf(mx, Dv[r]);
        mx = wmax64(mx);
        const float inv = __fdividef(1.f, mx);
        #pragma unroll
        for (int r = 0; r < 16; ++r) U[r] = Dv[r] * inv;
        const float l2tot = lac[0] + lac[1] + __log2f(mx);
        asm volatile("s_waitcnt lgkmcnt(0)" ::: "memory");
        #pragma unroll
        for (int m = 0; m < 4; ++m)
            #pragma unroll
            for (int j = 0; j < 4; ++j)
                slot[0][(8 * m + 4 * h + j) * 36 + c] = f2bf_rne(U[4 * m + j]);
        asm volatile("s_waitcnt lgkmcnt(0)" ::: "memory");
        u2v tg[4];
        #pragma unroll
        for (int g = 0; g < 4; ++g)
            tg[g] = *(const u2v*)(&slot[0][c * 36 + 8 * g + 4 * h]);
        unsigned short* gm = (unsigned short*)ws + SH_MATS2 + (size_t)blk * 1024 + l * 16;
        u4v s0; s0[0] = tg[0][0]; s0[1] = tg[0][1]; s0[2] = tg[1][0]; s0[3] = tg[1][1];
        u4v s1; s1[0] = tg[2][0]; s1[1] = tg[2][1]; s1[2] = tg[3][0]; s1[3] = tg[3][1];
        *(u4v*)(gm) = s0;
        *(u4v*)(gm + 8) = s1;
        if (l == 0) ws[WS_LS2 + blk] = scl[0] + scl[1] + LN2F * l2tot;
    }
}

// ================= k3: 16 chains of 8 + LDS tree + final loss =================
__global__ __launch_bounds__(1024, 1) void k3_final(
    const float* __restrict__ Y, const float* __restrict__ dTp,
    float* __restrict__ ws, float* __restrict__ out)
{
    __shared__ __align__(16) unsigned short slot[16][1152];
    __shared__ float sc[16];
    const int tid = threadIdx.x, wv = tid >> 6, l = tid & 63, h = l >> 5, c = l & 31;
    const unsigned short* mats2 = (const unsigned short*)ws + SH_MATS2;

    f16v zf;
    #pragma unroll
    for (int r = 0; r < 16; ++r) zf[r] = 0.f;

    const int idx0 = wv * 8;
    float lsv = (l < 8) ? ws[WS_LS2 + idx0 + l] : 0.f;
    float lssum = wsum64(lsv);
    f16v U;
    #pragma unroll
    for (int m = 0; m < 4; ++m)
        #pragma unroll
        for (int j = 0; j < 4; ++j)
            U[4 * m + j] = ((8 * m + 4 * h + j) == c) ? 1.f : 0.f;
    float l2a = 0.f;
    u4v pf[2][2];
    {
        const u4v* mp0 = (const u4v*)(mats2 + (size_t)idx0 * 1024) + l * 2;
        const u4v* mp1 = (const u4v*)(mats2 + (size_t)(idx0 + 1) * 1024) + l * 2;
        pf[0][0] = mp0[0]; pf[0][1] = mp0[1];
        pf[1][0] = mp1[0]; pf[1][1] = mp1[1];
    }
    for (int q = 0; q < 8; ++q) {
        const u4v a0 = pf[q & 1][0], a1 = pf[q & 1][1];
        if (q + 2 < 8) {
            const u4v* mp = (const u4v*)(mats2 + (size_t)(idx0 + q + 2) * 1024) + l * 2;
            pf[q & 1][0] = mp[0]; pf[q & 1][1] = mp[1];
        }
        f16v Dv = prodAU(a0, a1, U, zf);
        if ((q & 3) == 3) {
            float mx = Dv[0];
            #pragma unroll
            for (int r = 1; r < 16; ++r) mx = fmaxf(mx, Dv[r]);
            mx = wmax64(mx);
            const float inv = __fdividef(1.f, mx);
            #pragma unroll
            for (int r = 0; r < 16; ++r) U[r] = Dv[r] * inv;
            l2a += __log2f(mx);
        } else {
            U = Dv;
        }
    }
    #pragma unroll
    for (int m = 0; m < 4; ++m)
        #pragma unroll
        for (int j = 0; j < 4; ++j)
            slot[wv][(8 * m + 4 * h + j) * 36 + c] = f2bf_rne(U[4 * m + j]);
    if (l == 0) sc[wv] = lssum + LN2F * l2a;
    __syncthreads();

    for (int s = 1; s < 16; s <<= 1) {
        const int cnt = 16 / (2 * s);
        if (wv < cnt) {
            const int i = wv * 2 * s;
            s8v aA0, aA1, bB0, bB1;
            {
                u2v t0 = *(const u2v*)(&slot[i + s][c * 36 + 0 + 4 * h]);
                u2v t1 = *(const u2v*)(&slot[i + s][c * 36 + 8 + 4 * h]);
                u2v t2 = *(const u2v*)(&slot[i + s][c * 36 + 16 + 4 * h]);
                u2v t3 = *(const u2v*)(&slot[i + s][c * 36 + 24 + 4 * h]);
                u4v a0; a0[0] = t0[0]; a0[1] = t0[1]; a0[2] = t1[0]; a0[3] = t1[1];
                u4v a1; a1[0] = t2[0]; a1[1] = t2[1]; a1[2] = t3[0]; a1[3] = t3[1];
                aA0 = __builtin_bit_cast(s8v, a0);
                aA1 = __builtin_bit_cast(s8v, a1);
                #pragma unroll
                for (int j = 0; j < 4; ++j) {
                    bB0[j]     = (short)slot[i][(0  + 4 * h + j) * 36 + c];
                    bB0[4 + j] = (short)slot[i][(8  + 4 * h + j) * 36 + c];
                    bB1[j]     = (short)slot[i][(16 + 4 * h + j) * 36 + c];
                    bB1[4 + j] = (short)slot[i][(24 + 4 * h + j) * 36 + c];
                }
            }
            f16v Dv = mfma16(aA0, bB0, zf);
            Dv = mfma16(aA1, bB1, Dv);
            float mx = Dv[0];
            #pragma unroll
            for (int r = 1; r < 16; ++r) mx = fmaxf(mx, Dv[r]);
            mx = wmax64(mx);
            const float inv = __fdividef(1.f, mx);
            #pragma unroll
            for (int m = 0; m < 4; ++m)
                #pragma unroll
                for (int j = 0; j < 4; ++j)
                    slot[i][(8 * m + 4 * h + j) * 36 + c] = f2bf_rne(Dv[4 * m + j] * inv);
            if (l == 0) sc[i] = sc[i] + sc[i + s] + __logf(mx);
        }
        __syncthreads();
    }

    if (wv == 0) {
        float acc = 0.f;
        const float* Wf = ws + WS_WF;
        for (int dd = 0; dd < 128; ++dd) {
            const float yv = Y[dd & 63];
            const float f = (dd < 64) ? yv * yv : yv;
            acc = fmaf(f, Wf[dd * 32 + c], acc);
        }
        const float dt0 = dTp[0];
        const float ll0 = acc + ws[WS_CK + c] + ws[WS_AM1 + c] * __logf(dt0) - ws[WS_BB + c] * dt0;
        const float av = ws[WS_PI0 + c] + ll0;
        const float c0 = wmax32(av);
        const float a0 = __expf(av - c0);
        float part = 0.f;
        #pragma unroll
        for (int i = 0; i < 16; ++i) {
            const int ii = 16 * h + i;
            const float m = bf2f(slot[0][c * 36 + ii]);
            const float ai = __shfl(a0, ii);
            part = fmaf(m, ai, part);
        }
        const float srow = part + __shfl_xor(part, 32);
        const float tot = wsum32(srow);
        if (l == 0) out[(size_t)TT * DD] = -(sc[0] + c0 + __logf(tot));
    }
}

// ================= launcher =================
extern "C" void kernel_launch(void* const* d_in, const int* in_sizes, int n_in,
                              void* d_out, int out_size, void* d_ws, size_t ws_size,
                              hipStream_t stream)
{
    const float* Y   = (const float*)d_in[0];
    const float* dTp = (const float*)d_in[1];
    const float* A   = (const float*)d_in[2];
    const float* lab = (const float*)d_in[3];
    const float* mu  = (const float*)d_in[4];
    const float* lsg = (const float*)d_in[5];
    const float* pi  = (const float*)d_in[6];
    float* out = (float*)d_out;
    float* ws  = (float*)d_ws;

    hipLaunchKernelGGL(k0_prep, dim3(1), dim3(256), 0, stream, Y, A, lab, mu, lsg, pi, ws, out);
    hipLaunchKernelGGL(k1_scan, dim3(PCH / 4), dim3(256), 0, stream, Y, dTp, ws, out);
    hipLaunchKernelGGL(k2_combine, dim3(128), dim3(128), 0, stream, ws);
    hipLaunchKernelGGL(k3_final, dim3(1), dim3(1024), 0, stream, Y, dTp, ws, out);
}

// Round 11
// 182.386 us; speedup vs baseline: 1.0656x; 1.0164x over previous
//
#include <hip/hip_runtime.h>
#include <stdint.h>

// ---------------- problem constants ----------------
#define TT 262144
#define KK 32
#define DD 64
#define LSTEP 32               // scan steps per chunk
#define PCH 8192               // chunks (transitions t=1..T-1; last chunk has 31 steps)

typedef __attribute__((ext_vector_type(4)))  float f4v;
typedef __attribute__((ext_vector_type(16))) float f16v;
typedef __attribute__((ext_vector_type(4)))  short s4v;
typedef __attribute__((ext_vector_type(8)))  short s8v;
typedef __attribute__((ext_vector_type(8)))  __bf16 bf8v;
typedef __attribute__((ext_vector_type(2)))  unsigned int u2v;
typedef __attribute__((ext_vector_type(4)))  unsigned int u4v;

// ---------------- ws layout ----------------
// ushort-unit offsets (prep region)
#define WS_AFRAG_US 0          // ushort[1024] : Anorm^T frags [g2:2][lane:64][e:8] (K=16 order)
#define WS_WFRAG_US 1024       // ushort[4096] : W frags      [s2:8][lane:64][e:8] (K=16 order)
// float-unit offsets
#define WS_WF    2560          // float[4096]  : W fp32 [dd:128][k:32] (for k3 ll0)
#define WS_CK    6656          // float[32]
#define WS_AM1   6688          // float[32]
#define WS_BB    6720          // float[32]
#define WS_PI0   6752          // float[32]
#define WS_LS    8192          // float[PCH]   : chunk log-scales
#define WS_LS2   16384         // float[128]   : group log-scales
// short-unit offsets (matrix storage, bf16); lane's 16 ushorts = [old g:4][e:4];
// K=16 frag g2 = shorts 8*g2..8*g2+7 (concat of old K=8 frags 2g2, 2g2+1)
#define SH_MATS  33280                  // ushort[PCH*1024]  : chunk mats
#define SH_MATS2 (33280 + PCH*1024)     // ushort[128*1024]  : group mats
#define LN2F 0.69314718055994531f

__device__ __forceinline__ unsigned pkbf(float hi, float lo) {
    return __builtin_amdgcn_perm(__builtin_bit_cast(unsigned, hi),
                                 __builtin_bit_cast(unsigned, lo), 0x07060302u);
}
__device__ __forceinline__ unsigned short f2bf_rne(float f) {
    unsigned u = __builtin_bit_cast(unsigned, f);
    unsigned r = u + 0x7FFFu + ((u >> 16) & 1u);
    return (unsigned short)(r >> 16);
}
__device__ __forceinline__ float bf2f(unsigned short u) {
    return __builtin_bit_cast(float, (unsigned)u << 16);
}
__device__ __forceinline__ float wmax32(float v) {
    v = fmaxf(v, __shfl_xor(v, 1));  v = fmaxf(v, __shfl_xor(v, 2));
    v = fmaxf(v, __shfl_xor(v, 4));  v = fmaxf(v, __shfl_xor(v, 8));
    v = fmaxf(v, __shfl_xor(v, 16));
    return v;
}
__device__ __forceinline__ float wmax64(float v) {
    v = wmax32(v); v = fmaxf(v, __shfl_xor(v, 32));
    return v;
}
__device__ __forceinline__ float wsum32(float v) {
    v += __shfl_xor(v, 1); v += __shfl_xor(v, 2); v += __shfl_xor(v, 4);
    v += __shfl_xor(v, 8); v += __shfl_xor(v, 16);
    return v;
}
__device__ __forceinline__ float wsum64(float v) {
    v = wsum32(v); v += __shfl_xor(v, 32);
    return v;
}
__device__ __forceinline__ float wval(int dd, int k, const float* mu, const float* lsg) {
    int d = dd & 63;
    float lv = lsg[k * DD + d];
    float iv = __expf(-2.f * lv);
    return (dd < DD) ? (-0.5f * iv) : (mu[k * DD + d] * iv);
}
// gfx950 K=16 bf16 MFMA (full-rate; the _1k K=8 op occupies the same pipe slot for half the FLOPs)
__device__ __forceinline__ f16v mfma16(s8v a, s8v b, f16v c) {
    return __builtin_amdgcn_mfma_f32_32x32x16_bf16(
        __builtin_bit_cast(bf8v, a), __builtin_bit_cast(bf8v, b), c, 0, 0, 0);
}

// ================= k0: constants / fragment preformat =================
__global__ void k0_prep(const float* __restrict__ Y, const float* __restrict__ A,
                        const float* __restrict__ lab, const float* __restrict__ mu,
                        const float* __restrict__ lsg, const float* __restrict__ pi,
                        float* __restrict__ ws, float* __restrict__ out)
{
    __shared__ float lseA[KK];
    const int tid = threadIdx.x;
    if (tid < KK) {
        float m = -1e30f;
        for (int j = 0; j < KK; ++j) m = fmaxf(m, A[tid * KK + j]);
        float s = 0.f;
        for (int j = 0; j < KK; ++j) s += __expf(A[tid * KK + j] - m);
        lseA[tid] = m + __logf(s);

        float mp = -1e30f;
        for (int j = 0; j < KK; ++j) mp = fmaxf(mp, pi[j]);
        float sp = 0.f;
        for (int j = 0; j < KK; ++j) sp += __expf(pi[j] - mp);
        ws[WS_PI0 + tid] = pi[tid] - (mp + __logf(sp));

        float la = lab[tid * 2 + 0], lb = lab[tid * 2 + 1];
        float a = __expf(la), b = __expf(lb);
        float c1 = 0.f, c2 = 0.f;
        for (int d = 0; d < DD; ++d) {
            float lv = lsg[tid * DD + d];
            float mv = mu[tid * DD + d];
            c1 -= lv;
            c2 += mv * mv * __expf(-2.f * lv);
        }
        ws[WS_CK + tid]  = a * lb - lgammaf(a) + c1 - 0.5f * c2 - 32.f * 1.8378770664093453f;
        ws[WS_AM1 + tid] = a - 1.f;
        ws[WS_BB + tid]  = b;
    }
    __syncthreads();
    unsigned short* us = (unsigned short*)ws;
    // A frags, K=16 order: [g2:2][lane:64][e:8]; k = 16*g2 + 8*(e>>2) + 4*h + (e&3)
    for (int idx = tid; idx < 1024; idx += 256) {
        int g2 = idx >> 9, rem = idx & 511, ln = rem >> 3, e = rem & 7;
        int m = 16 * g2 + 8 * (e >> 2) + 4 * (ln >> 5) + (e & 3), i = ln & 31;
        us[WS_AFRAG_US + idx] = f2bf_rne(__expf(A[m * KK + i] - lseA[m]));
    }
    // W frags, K=16 order: [s2:8][lane:64][e:8]; dd = 16*s2 + 8*(e>>2) + 4*h + (e&3)
    // s2 0..3 pair with y^2 (dd 0..63), s2 4..7 pair with y (dd 64..127)
    for (int idx = tid; idx < 4096; idx += 256) {
        int s2 = idx >> 9, rem = idx & 511, ln = rem >> 3, e = rem & 7;
        int dd = 16 * s2 + 8 * (e >> 2) + 4 * (ln >> 5) + (e & 3);
        us[WS_WFRAG_US + idx] = f2bf_rne(wval(dd, ln & 31, mu, lsg));
    }
    for (int idx = tid; idx < 4096; idx += 256) {
        int dd = idx >> 5, k = idx & 31;
        ws[WS_WF + idx] = wval(dd, k, mu, lsg);
    }
    if (tid < DD) out[tid] = Y[tid];   // h row 0
}

// ================= k1: chunk scan (1 wave = 1 chunk of 32 steps) =================
// R10 base (185.4us verified; bf16 Y-frag staging with fused coalesced h write, f32 E
// stride-36 aliasing dead Y, shfl reductions, 19456B LDS) + the one lever with a
// measured causal effect (R10: every-4 -> every-8 rescale = -4.5us, ~1:1 with serial
// chain removal): rescale every 16 steps. Safety: e<=1 with per-timestep max=1 so
// S-max only decays; per-step decay floor ~ max softmax transition weight (~0.1) ->
// 16-step decay >= ~1e-16 >> f32/bf16 min normal (~1.2e-38).
__global__ __launch_bounds__(256, 6) void k1_scan(
    const float* __restrict__ Y, const float* __restrict__ dTp,
    float* __restrict__ ws, float* __restrict__ out)
{
    __shared__ __align__(16) float Ebuf[4][1152];        // per-wave: Ybf(4KB) / E(4.5KB) / Tb alias
    __shared__ __align__(16) float dtv[4][32], dtl[4][32];

    const int tid = threadIdx.x;
    const int wv = tid >> 6, l = tid & 63, h = l >> 5, c = l & 31;
    const int p = blockIdx.x * 4 + wv;
    const int t0 = 1 + p * LSTEP;
    const int nsteps = min(LSTEP, TT - t0);

    const unsigned short* afr = (const unsigned short*)ws + WS_AFRAG_US;
    const unsigned short* wfr = (const unsigned short*)ws + WS_WFRAG_US;

    const float cK = ws[WS_CK + c], am1 = ws[WS_AM1 + c], bb = ws[WS_BB + c];

    if (l < 32) {
        int t = t0 + l;
        float dv = (t < TT) ? dTp[t] : 1.f;
        dtv[wv][l] = dv;
        dtl[wv][l] = __logf(dv);
    }

    f16v zf;
    #pragma unroll
    for (int r = 0; r < 16; ++r) zf[r] = 0.f;

    unsigned short* Ybf = (unsigned short*)&Ebuf[wv][0];   // 2048 ushorts, frag order
    float* E = &Ebuf[wv][0];                                // aliases Ybf (Y dead when E written)

    // ---- coalesced Y stage -> LDS bf16 frags, fused coalesced h write ----
    {
        const size_t gbase = (size_t)t0 * DD;
        const int rr = l & 3, cb = l >> 2;
        const int g2s = cb >> 2, bs = (cb >> 1) & 1, hs = cb & 1;
        #pragma unroll
        for (int i = 0; i < 8; ++i) {
            const size_t gi = gbase + (size_t)i * 256 + (size_t)(rr * 64 + cb * 4);
            f4v y4; y4[0] = 0.f; y4[1] = 0.f; y4[2] = 0.f; y4[3] = 0.f;
            const bool ok = gi < (size_t)TT * DD;
            if (ok) y4 = *(const f4v*)(Y + gi);
            if (ok) *(f4v*)(out + gi) = y4;
            const int row = i * 4 + rr;
            const int off = g2s * 512 + (32 * hs + row) * 8 + 4 * bs;   // ushort units, 8B-aligned
            u2v pw; pw[0] = pkbf(y4[1], y4[0]); pw[1] = pkbf(y4[3], y4[2]);
            *(u2v*)(Ybf + off) = pw;
        }
    }
    asm volatile("s_waitcnt lgkmcnt(0)" ::: "memory");  // frag writes visible to own wave

    // ---- emission ll tile via K=16 MFMA; raw-y frag IS the LDS read ----
    f16v acc = zf;
    s8v raws[4];
    #pragma unroll
    for (int g2 = 0; g2 < 4; ++g2) {
        const s8v yf = *(const s8v*)(Ybf + g2 * 512 + l * 8);   // 16B/lane contiguous
        raws[g2] = yf;
        u4v qp;
        #pragma unroll
        for (int e2 = 0; e2 < 4; ++e2) {
            const float f0 = bf2f((unsigned short)yf[2 * e2]);
            const float f1 = bf2f((unsigned short)yf[2 * e2 + 1]);
            qp[e2] = pkbf(f1 * f1, f0 * f0);
        }
        const s8v wf = *(const s8v*)(wfr + g2 * 512 + l * 8);
        acc = mfma16(__builtin_bit_cast(s8v, qp), wf, acc);
    }
    #pragma unroll
    for (int g2 = 0; g2 < 4; ++g2) {
        const s8v wf = *(const s8v*)(wfr + (4 + g2) * 512 + l * 8);
        acc = mfma16(raws[g2], wf, acc);
    }

    // ---- A^T frags (two K=16 groups) ----
    const s8v aF0 = *(const s8v*)(afr + l * 8);
    const s8v aF1 = *(const s8v*)(afr + 512 + l * 8);

    // ---- ll -> c_t (row max over states), e = exp(ll-c) into E (aliases Ybf; Y dead) ----
    float csv = 0.f;
    #pragma unroll
    for (int m = 0; m < 4; ++m) {
        const f4v dv4 = *(const f4v*)(&dtv[wv][8 * m + 4 * h]);
        const f4v dl4 = *(const f4v*)(&dtl[wv][8 * m + 4 * h]);
        #pragma unroll
        for (int j = 0; j < 4; ++j) {
            const int row = 8 * m + 4 * h + j;
            float llv = acc[4 * m + j] + cK + am1 * dl4[j] - bb * dv4[j];
            float cm = wmax32(llv);
            E[row * 36 + c] = __expf(llv - cm);
            csv += (row < nsteps) ? cm : 0.f;
        }
    }
    float cacc = wsum64(csv) * (1.f / 32.f);

    asm volatile("s_waitcnt lgkmcnt(0)" ::: "memory");  // E visible to own wave

    // ---- scan: S <- diag(e_t) * Anorm^T * S ----
    f16v S;
    #pragma unroll
    for (int m = 0; m < 4; ++m)
        #pragma unroll
        for (int j = 0; j < 4; ++j)
            S[4 * m + j] = ((8 * m + 4 * h + j) == c) ? 1.f : 0.f;
    float l2acc = 0.f;

    auto step = [&](int n) {
        u4v b0, b1;
        b0[0] = pkbf(S[1],  S[0]);  b0[1] = pkbf(S[3],  S[2]);
        b0[2] = pkbf(S[5],  S[4]);  b0[3] = pkbf(S[7],  S[6]);
        b1[0] = pkbf(S[9],  S[8]);  b1[1] = pkbf(S[11], S[10]);
        b1[2] = pkbf(S[13], S[12]); b1[3] = pkbf(S[15], S[14]);
        f16v Dv = mfma16(aF0, __builtin_bit_cast(s8v, b0), zf);
        Dv = mfma16(aF1, __builtin_bit_cast(s8v, b1), Dv);
        #pragma unroll
        for (int m = 0; m < 4; ++m) {
            const f4v e4 = *(const f4v*)(E + n * 36 + 8 * m + 4 * h);  // 2-addr broadcast
            S[4 * m + 0] = Dv[4 * m + 0] * e4[0];
            S[4 * m + 1] = Dv[4 * m + 1] * e4[1];
            S[4 * m + 2] = Dv[4 * m + 2] * e4[2];
            S[4 * m + 3] = Dv[4 * m + 3] * e4[3];
        }
    };
    auto rescale = [&]() {
        float mx = S[0];
        #pragma unroll
        for (int r = 1; r < 16; ++r) mx = fmaxf(mx, S[r]);
        mx = wmax64(mx);
        const float inv = __fdividef(1.f, mx);
        #pragma unroll
        for (int r = 0; r < 16; ++r) S[r] *= inv;
        l2acc += __log2f(mx);
    };

    if (p != PCH - 1) {
        #pragma unroll
        for (int n = 0; n < LSTEP; ++n) {
            step(n);
            if ((n & 15) == 15) rescale();   // every-16: S-max only decays, >=~1e-16 over 16 steps
        }
    } else {
        for (int n = 0; n < nsteps; ++n) {
            step(n);
            if ((n & 15) == 15) rescale();
        }
    }

    // ---- transpose S (C-layout) -> frag order bf16, coalesced store ----
    unsigned short* Tb = (unsigned short*)&Ebuf[wv][0];    // E is dead now
    asm volatile("s_waitcnt lgkmcnt(0)" ::: "memory");
    #pragma unroll
    for (int m = 0; m < 4; ++m)
        #pragma unroll
        for (int j = 0; j < 4; ++j)
            Tb[(8 * m + 4 * h + j) * 36 + c] = f2bf_rne(S[4 * m + j]);
    asm volatile("s_waitcnt lgkmcnt(0)" ::: "memory");
    u2v tg0 = *(const u2v*)(Tb + c * 36 + 0  + 4 * h);
    u2v tg1 = *(const u2v*)(Tb + c * 36 + 8  + 4 * h);
    u2v tg2 = *(const u2v*)(Tb + c * 36 + 16 + 4 * h);
    u2v tg3 = *(const u2v*)(Tb + c * 36 + 24 + 4 * h);
    unsigned short* gm = (unsigned short*)ws + SH_MATS + (size_t)p * 1024 + l * 16;
    u4v s0; s0[0] = tg0[0]; s0[1] = tg0[1]; s0[2] = tg1[0]; s0[3] = tg1[1];
    u4v s1; s1[0] = tg2[0]; s1[1] = tg2[1]; s1[2] = tg3[0]; s1[3] = tg3[1];
    *(u4v*)(gm) = s0;
    *(u4v*)(gm + 8) = s1;
    if (l == 0) ws[WS_LS + p] = cacc + LN2F * l2acc;
}

// ---- helper: one product step  U <- A_mat * U  (A from 2 uint4 regs = two K=16 frags) ----
__device__ __forceinline__ f16v prodAU(const u4v a0, const u4v a1, const f16v U, const f16v zf) {
    u4v b0, b1;
    b0[0] = pkbf(U[1],  U[0]);  b0[1] = pkbf(U[3],  U[2]);
    b0[2] = pkbf(U[5],  U[4]);  b0[3] = pkbf(U[7],  U[6]);
    b1[0] = pkbf(U[9],  U[8]);  b1[1] = pkbf(U[11], U[10]);
    b1[2] = pkbf(U[13], U[12]); b1[3] = pkbf(U[15], U[14]);
    f16v Dv = mfma16(__builtin_bit_cast(s8v, a0), __builtin_bit_cast(s8v, b0), zf);
    Dv = mfma16(__builtin_bit_cast(s8v, a1), __builtin_bit_cast(s8v, b1), Dv);
    return Dv;
}

// ================= k2: combine 64 chunk mats per block (2 waves x 32 + pair) =================
// rescale every 8 products (was 4): entries of products of max~1 nonneg 32x32 mats
// grow <= 32^8 ~ 1e12, far inside f32/bf16 exponent range.
__global__ __launch_bounds__(128, 1) void k2_combine(float* __restrict__ ws)
{
    __shared__ __align__(16) unsigned short slot[2][1152];  // row-major, stride 36
    __shared__ float scl[2], lac[2];
    const int tid = threadIdx.x, wv = tid >> 6, l = tid & 63, h = l >> 5, c = l & 31;
    const int blk = blockIdx.x;
    const int idx0 = blk * 64 + wv * 32;
    const unsigned short* mats = (const unsigned short*)ws + SH_MATS;

    float lsv = (l < 32) ? ws[WS_LS + idx0 + l] : 0.f;
    float lssum = wsum64(lsv);

    f16v zf;
    #pragma unroll
    for (int r = 0; r < 16; ++r) zf[r] = 0.f;
    f16v U;
    #pragma unroll
    for (int m = 0; m < 4; ++m)
        #pragma unroll
        for (int j = 0; j < 4; ++j)
            U[4 * m + j] = ((8 * m + 4 * h + j) == c) ? 1.f : 0.f;
    float l2a = 0.f;

    u4v pf[2][2];
    {
        const u4v* mp0 = (const u4v*)(mats + (size_t)idx0 * 1024) + l * 2;
        const u4v* mp1 = (const u4v*)(mats + (size_t)(idx0 + 1) * 1024) + l * 2;
        pf[0][0] = mp0[0]; pf[0][1] = mp0[1];
        pf[1][0] = mp1[0]; pf[1][1] = mp1[1];
    }
    for (int q = 0; q < 32; ++q) {
        const u4v a0 = pf[q & 1][0], a1 = pf[q & 1][1];
        if (q + 2 < 32) {
            const u4v* mp = (const u4v*)(mats + (size_t)(idx0 + q + 2) * 1024) + l * 2;
            pf[q & 1][0] = mp[0]; pf[q & 1][1] = mp[1];
        }
        f16v Dv = prodAU(a0, a1, U, zf);
        if ((q & 7) == 7) {
            float mx = Dv[0];
            #pragma unroll
            for (int r = 1; r < 16; ++r) mx = fmaxf(mx, Dv[r]);
            mx = wmax64(mx);
            const float inv = __fdividef(1.f, mx);
            #pragma unroll
            for (int r = 0; r < 16; ++r) U[r] = Dv[r] * inv;
            l2a += __log2f(mx);
        } else {
            U = Dv;
        }
    }
    #pragma unroll
    for (int m = 0; m < 4; ++m)
        #pragma unroll
        for (int j = 0; j < 4; ++j)
            slot[wv][(8 * m + 4 * h + j) * 36 + c] = f2bf_rne(U[4 * m + j]);
    if (l == 0) { scl[wv] = lssum; lac[wv] = l2a; }
    __syncthreads();

    if (wv == 0) {
        u4v a0, a1;
        {
            u2v t0 = *(const u2v*)(&slot[1][c * 36 + 0 + 4 * h]);
            u2v t1 = *(const u2v*)(&slot[1][c * 36 + 8 + 4 * h]);
            u2v t2 = *(const u2v*)(&slot[1][c * 36 + 16 + 4 * h]);
            u2v t3 = *(const u2v*)(&slot[1][c * 36 + 24 + 4 * h]);
            a0[0] = t0[0]; a0[1] = t0[1]; a0[2] = t1[0]; a0[3] = t1[1];
            a1[0] = t2[0]; a1[1] = t2[1]; a1[2] = t3[0]; a1[3] = t3[1];
        }
        f16v Dv = prodAU(a0, a1, U, zf);
        float mx = Dv[0];
        #pragma unroll
        for (int r = 1; r < 16; ++r) mx = fmaxf(mx, Dv[r]);
        mx = wmax64(mx);
        const float inv = __fdividef(1.f, mx);
        #pragma unroll
        for (int r = 0; r < 16; ++r) U[r] = Dv[r] * inv;
        const float l2tot = lac[0] + lac[1] + __log2f(mx);
        asm volatile("s_waitcnt lgkmcnt(0)" ::: "memory");
        #pragma unroll
        for (int m = 0; m < 4; ++m)
            #pragma unroll
            for (int j = 0; j < 4; ++j)
                slot[0][(8 * m + 4 * h + j) * 36 + c] = f2bf_rne(U[4 * m + j]);
        asm volatile("s_waitcnt lgkmcnt(0)" ::: "memory");
        u2v tg[4];
        #pragma unroll
        for (int g = 0; g < 4; ++g)
            tg[g] = *(const u2v*)(&slot[0][c * 36 + 8 * g + 4 * h]);
        unsigned short* gm = (unsigned short*)ws + SH_MATS2 + (size_t)blk * 1024 + l * 16;
        u4v s0; s0[0] = tg[0][0]; s0[1] = tg[0][1]; s0[2] = tg[1][0]; s0[3] = tg[1][1];
        u4v s1; s1[0] = tg[2][0]; s1[1] = tg[2][1]; s1[2] = tg[3][0]; s1[3] = tg[3][1];
        *(u4v*)(gm) = s0;
        *(u4v*)(gm + 8) = s1;
        if (l == 0) ws[WS_LS2 + blk] = scl[0] + scl[1] + LN2F * l2tot;
    }
}

// ================= k3: 16 chains of 8 + LDS tree + final loss =================
__global__ __launch_bounds__(1024, 1) void k3_final(
    const float* __restrict__ Y, const float* __restrict__ dTp,
    float* __restrict__ ws, float* __restrict__ out)
{
    __shared__ __align__(16) unsigned short slot[16][1152];
    __shared__ float sc[16];
    const int tid = threadIdx.x, wv = tid >> 6, l = tid & 63, h = l >> 5, c = l & 31;
    const unsigned short* mats2 = (const unsigned short*)ws + SH_MATS2;

    f16v zf;
    #pragma unroll
    for (int r = 0; r < 16; ++r) zf[r] = 0.f;

    const int idx0 = wv * 8;
    float lsv = (l < 8) ? ws[WS_LS2 + idx0 + l] : 0.f;
    float lssum = wsum64(lsv);
    f16v U;
    #pragma unroll
    for (int m = 0; m < 4; ++m)
        #pragma unroll
        for (int j = 0; j < 4; ++j)
            U[4 * m + j] = ((8 * m + 4 * h + j) == c) ? 1.f : 0.f;
    float l2a = 0.f;
    u4v pf[2][2];
    {
        const u4v* mp0 = (const u4v*)(mats2 + (size_t)idx0 * 1024) + l * 2;
        const u4v* mp1 = (const u4v*)(mats2 + (size_t)(idx0 + 1) * 1024) + l * 2;
        pf[0][0] = mp0[0]; pf[0][1] = mp0[1];
        pf[1][0] = mp1[0]; pf[1][1] = mp1[1];
    }
    for (int q = 0; q < 8; ++q) {
        const u4v a0 = pf[q & 1][0], a1 = pf[q & 1][1];
        if (q + 2 < 8) {
            const u4v* mp = (const u4v*)(mats2 + (size_t)(idx0 + q + 2) * 1024) + l * 2;
            pf[q & 1][0] = mp[0]; pf[q & 1][1] = mp[1];
        }
        f16v Dv = prodAU(a0, a1, U, zf);
        if ((q & 7) == 7) {
            float mx = Dv[0];
            #pragma unroll
            for (int r = 1; r < 16; ++r) mx = fmaxf(mx, Dv[r]);
            mx = wmax64(mx);
            const float inv = __fdividef(1.f, mx);
            #pragma unroll
            for (int r = 0; r < 16; ++r) U[r] = Dv[r] * inv;
            l2a += __log2f(mx);
        } else {
            U = Dv;
        }
    }
    #pragma unroll
    for (int m = 0; m < 4; ++m)
        #pragma unroll
        for (int j = 0; j < 4; ++j)
            slot[wv][(8 * m + 4 * h + j) * 36 + c] = f2bf_rne(U[4 * m + j]);
    if (l == 0) sc[wv] = lssum + LN2F * l2a;
    __syncthreads();

    for (int s = 1; s < 16; s <<= 1) {
        const int cnt = 16 / (2 * s);
        if (wv < cnt) {
            const int i = wv * 2 * s;
            s8v aA0, aA1, bB0, bB1;
            {
                u2v t0 = *(const u2v*)(&slot[i + s][c * 36 + 0 + 4 * h]);
                u2v t1 = *(const u2v*)(&slot[i + s][c * 36 + 8 + 4 * h]);
                u2v t2 = *(const u2v*)(&slot[i + s][c * 36 + 16 + 4 * h]);
                u2v t3 = *(const u2v*)(&slot[i + s][c * 36 + 24 + 4 * h]);
                u4v a0; a0[0] = t0[0]; a0[1] = t0[1]; a0[2] = t1[0]; a0[3] = t1[1];
                u4v a1; a1[0] = t2[0]; a1[1] = t2[1]; a1[2] = t3[0]; a1[3] = t3[1];
                aA0 = __builtin_bit_cast(s8v, a0);
                aA1 = __builtin_bit_cast(s8v, a1);
                #pragma unroll
                for (int j = 0; j < 4; ++j) {
                    bB0[j]     = (short)slot[i][(0  + 4 * h + j) * 36 + c];
                    bB0[4 + j] = (short)slot[i][(8  + 4 * h + j) * 36 + c];
                    bB1[j]     = (short)slot[i][(16 + 4 * h + j) * 36 + c];
                    bB1[4 + j] = (short)slot[i][(24 + 4 * h + j) * 36 + c];
                }
            }
            f16v Dv = mfma16(aA0, bB0, zf);
            Dv = mfma16(aA1, bB1, Dv);
            float mx = Dv[0];
            #pragma unroll
            for (int r = 1; r < 16; ++r) mx = fmaxf(mx, Dv[r]);
            mx = wmax64(mx);
            const float inv = __fdividef(1.f, mx);
            #pragma unroll
            for (int m = 0; m < 4; ++m)
                #pragma unroll
                for (int j = 0; j < 4; ++j)
                    slot[i][(8 * m + 4 * h + j) * 36 + c] = f2bf_rne(Dv[4 * m + j] * inv);
            if (l == 0) sc[i] = sc[i] + sc[i + s] + __logf(mx);
        }
        __syncthreads();
    }

    if (wv == 0) {
        float acc = 0.f;
        const float* Wf = ws + WS_WF;
        for (int dd = 0; dd < 128; ++dd) {
            const float yv = Y[dd & 63];
            const float f = (dd < 64) ? yv * yv : yv;
            acc = fmaf(f, Wf[dd * 32 + c], acc);
        }
        const float dt0 = dTp[0];
        const float ll0 = acc + ws[WS_CK + c] + ws[WS_AM1 + c] * __logf(dt0) - ws[WS_BB + c] * dt0;
        const float av = ws[WS_PI0 + c] + ll0;
        const float c0 = wmax32(av);
        const float a0 = __expf(av - c0);
        float part = 0.f;
        #pragma unroll
        for (int i = 0; i < 16; ++i) {
            const int ii = 16 * h + i;
            const float m = bf2f(slot[0][c * 36 + ii]);
            const float ai = __shfl(a0, ii);
            part = fmaf(m, ai, part);
        }
        const float srow = part + __shfl_xor(part, 32);
        const float tot = wsum32(srow);
        if (l == 0) out[(size_t)TT * DD] = -(sc[0] + c0 + __logf(tot));
    }
}

// ================= launcher =================
extern "C" void kernel_launch(void* const* d_in, const int* in_sizes, int n_in,
                              void* d_out, int out_size, void* d_ws, size_t ws_size,
                              hipStream_t stream)
{
    const float* Y   = (const float*)d_in[0];
    const float* dTp = (const float*)d_in[1];
    const float* A   = (const float*)d_in[2];
    const float* lab = (const float*)d_in[3];
    const float* mu  = (const float*)d_in[4];
    const float* lsg = (const float*)d_in[5];
    const float* pi  = (const float*)d_in[6];
    float* out = (float*)d_out;
    float* ws  = (float*)d_ws;

    hipLaunchKernelGGL(k0_prep, dim3(1), dim3(256), 0, stream, Y, A, lab, mu, lsg, pi, ws, out);
    hipLaunchKernelGGL(k1_scan, dim3(PCH / 4), dim3(256), 0, stream, Y, dTp, ws, out);
    hipLaunchKernelGGL(k2_combine, dim3(128), dim3(128), 0, stream, ws);
    hipLaunchKernelGGL(k3_final, dim3(1), dim3(1024), 0, stream, Y, dTp, ws, out);
}